// Round 4
// baseline (480.588 us; speedup 1.0000x reference)
//
#include <hip/hip_runtime.h>

typedef float f32x4 __attribute__((ext_vector_type(4)));
typedef unsigned int u32x4 __attribute__((ext_vector_type(4)));
typedef __bf16 bf16x8_t __attribute__((ext_vector_type(8)));
typedef __bf16 bf16x4_t __attribute__((ext_vector_type(4)));

#define DEVFN static __device__ __forceinline__

constexpr int BHN = 16;    // B*H
constexpr int SN  = 2048;
constexpr int DN  = 64;
constexpr float SCL = 0.125f;   // 1/sqrt(64)
constexpr size_t CTXN = (size_t)BHN * SN * DN;   // 2,097,152 f32
constexpr int NK1 = 4;    // k-split chunks, pass 1
constexpr int NK2 = 4;    // k-split chunks, pass 2 (FAST path only)
constexpr int KT  = 32;   // k-rows per LDS tile

// ---- MFMA groups with INTERNAL hazard fencing (verified R2/R3).
DEVFN void qk2_mfma(f32x4& d, bf16x8_t a0, bf16x8_t b0, bf16x8_t a1, bf16x8_t b1) {
  asm volatile("s_nop 3\n\t"
               "v_mfma_f32_16x16x32_bf16 %0, %1, %2, %0\n\t"
               "v_mfma_f32_16x16x32_bf16 %0, %3, %4, %0\n\t"
               "s_nop 7\n\ts_nop 7"
               : "+v"(d) : "v"(a0), "v"(b0), "v"(a1), "v"(b1));
}

DEVFN void pv4_mfma(f32x4& c0, f32x4& c1, f32x4& c2, f32x4& c3, bf16x4_t pa,
                    bf16x4_t v0, bf16x4_t v1, bf16x4_t v2, bf16x4_t v3) {
  asm volatile("s_nop 3\n\t"
               "v_mfma_f32_16x16x16_bf16 %0, %4, %5, %0\n\t"
               "v_mfma_f32_16x16x16_bf16 %1, %4, %6, %1\n\t"
               "v_mfma_f32_16x16x16_bf16 %2, %4, %7, %2\n\t"
               "v_mfma_f32_16x16x16_bf16 %3, %4, %8, %3\n\t"
               "s_nop 7\n\ts_nop 7"
               : "+v"(c0), "+v"(c1), "+v"(c2), "+v"(c3)
               : "v"(pa), "v"(v0), "v"(v1), "v"(v2), "v"(v3));
}

DEVFN bf16x8_t load8bf(const float* p) {
  f32x4 a = *(const f32x4*)p;
  f32x4 b = *(const f32x4*)(p + 4);
  bf16x8_t r;
  r[0]=(__bf16)a[0]; r[1]=(__bf16)a[1]; r[2]=(__bf16)a[2]; r[3]=(__bf16)a[3];
  r[4]=(__bf16)b[0]; r[5]=(__bf16)b[1]; r[6]=(__bf16)b[2]; r[7]=(__bf16)b[3];
  return r;
}

// LDS tile addressing: bf16 [KT][64], row = 128 B, XOR-swizzled 16B slots (G4).
DEVFN int swzoff(int row, int bc) { return row * 128 + (bc ^ ((row & 7) << 4)); }

// thread tid stages rows (tid>>4) and (tid>>4)+16, f32 cols (tid&15)*4..+3
DEVFN void stage_put(char* buf, int tid, f32x4 v0, f32x4 v1) {
  const int r  = tid >> 4;
  const int bc = (tid & 15) * 8;
  bf16x4_t a = {(__bf16)v0[0], (__bf16)v0[1], (__bf16)v0[2], (__bf16)v0[3]};
  bf16x4_t b = {(__bf16)v1[0], (__bf16)v1[1], (__bf16)v1[2], (__bf16)v1[3]};
  *(bf16x4_t*)&buf[swzoff(r, bc)]      = a;
  *(bf16x4_t*)&buf[swzoff(r + 16, bc)] = b;
}

// ---- detect mask storage width: fl==1 -> uint8 bytes; else 4-byte words.
__global__ void detect_mask_kernel(const unsigned int* __restrict__ mraw,
                                   unsigned int* __restrict__ flag) {
  unsigned int f = 0;
  for (int i = threadIdx.x; i < 4096; i += 64) {
    unsigned int w = mraw[i];
    if (w == 0x3F800000u) f |= 2u;
    else if (w > 1u) f |= 1u;
  }
  unsigned long long b2 = __ballot((f & 2u) != 0u);
  unsigned long long b1 = __ballot((f & 1u) != 0u);
  if (threadIdx.x == 0) *flag = b2 ? 2u : (b1 ? 1u : 0u);
}

// ---- pack mask -> bitmask (bit=1 means masked), coalesced wave-ballot.
__global__ __launch_bounds__(256) void pack_mask_kernel(
    const unsigned int* __restrict__ mraw, unsigned long long* __restrict__ bm,
    const unsigned int* __restrict__ flag) {
  const int lane = threadIdx.x & 63;
  const int wid  = blockIdx.x * (blockDim.x >> 6) + (threadIdx.x >> 6);
  const int nw   = gridDim.x * (blockDim.x >> 6);
  if (*flag != 1u) {
    const int W = BHN * SN * (SN / 64);          // 1,048,576
    for (int w = wid; w < W; w += nw) {
      unsigned int v = __builtin_nontemporal_load(mraw + (size_t)w * 64 + lane);
      unsigned long long bits = __ballot(v != 0u);
      if (lane == 0) bm[w] = bits;
    }
  } else {
    const int W = BHN * SN * (SN / 256);         // 262,144
    for (int w = wid; w < W; w += nw) {
      unsigned int v = __builtin_nontemporal_load(mraw + (size_t)w * 64 + lane);
      #pragma unroll
      for (int b = 0; b < 4; ++b) {
        unsigned long long bits = __ballot(((v >> (8 * b)) & 0xFFu) != 0u);
        if (lane == 0) bm[(size_t)w * 4 + b] = bits;
      }
    }
  }
}

// ---- pass 1: per-row denom l = sum_k exp(s). LDS-staged K, double-buffered.
__global__ __launch_bounds__(256, 8) void attn_l_kernel(
    const float* __restrict__ Q, const float* __restrict__ K,
    const unsigned int* __restrict__ bm32,
    float* __restrict__ lpart, int pstride, int nchunks) {
  __shared__ __align__(16) char Kl[2][KT * 128];
  const int tid  = threadIdx.x;
  const int lane = tid & 63, wv = tid >> 6;
  const int qr   = lane & 15, g = lane >> 4;
  const int bh   = blockIdx.y, c = blockIdx.z;
  const int q    = blockIdx.x * 64 + wv * 16 + qr;
  const int CS   = SN / nchunks, kbeg = c * CS, NT = CS / KT;
  const size_t base = (size_t)bh * (SN * DN);
  const float* Kc = K + base;
  const int sr = tid >> 4, sc = (tid & 15) * 4;

  const float* qrow = Q + base + (size_t)q * DN;
  bf16x8_t qf0 = load8bf(qrow + 8 * g);
  bf16x8_t qf1 = load8bf(qrow + 32 + 8 * g);
  const size_t row = (size_t)bh * SN + q;
  const unsigned int* bmrow = bm32 + row * (SN / 32);

  f32x4 gk0 = *(const f32x4*)(Kc + (size_t)(kbeg + sr) * DN + sc);
  f32x4 gk1 = *(const f32x4*)(Kc + (size_t)(kbeg + sr + 16) * DN + sc);
  stage_put(Kl[0], tid, gk0, gk1);
  __syncthreads();

  float l = 0.f;
  for (int t = 0; t < NT; ++t) {
    const int kt = kbeg + t * KT;
    const bool pf = (t + 1 < NT);
    if (pf) {
      gk0 = *(const f32x4*)(Kc + (size_t)(kt + KT + sr) * DN + sc);
      gk1 = *(const f32x4*)(Kc + (size_t)(kt + KT + sr + 16) * DN + sc);
    }
    const char* Kb = Kl[t & 1];
    const unsigned int bmw = bmrow[kt >> 5];
    #pragma unroll
    for (int s = 0; s < 2; ++s) {
      const int kl = s * 16;
      const int rk = kl + qr;
      bf16x8_t kf0 = *(const bf16x8_t*)&Kb[swzoff(rk, 16 * g)];
      bf16x8_t kf1 = *(const bf16x8_t*)&Kb[swzoff(rk, 64 + 16 * g)];
      f32x4 acc = {0.f, 0.f, 0.f, 0.f};
      qk2_mfma(acc, kf0, qf0, kf1, qf1);
      const int sh = kl + 4 * g;
      float e0 = ((bmw >> (sh + 0)) & 1u) ? 0.f : __expf(acc[0] * SCL);
      float e1 = ((bmw >> (sh + 1)) & 1u) ? 0.f : __expf(acc[1] * SCL);
      float e2 = ((bmw >> (sh + 2)) & 1u) ? 0.f : __expf(acc[2] * SCL);
      float e3 = ((bmw >> (sh + 3)) & 1u) ? 0.f : __expf(acc[3] * SCL);
      l += e0 + e1 + e2 + e3;
    }
    if (pf) stage_put(Kl[(t + 1) & 1], tid, gk0, gk1);
    __syncthreads();
  }
  l = l + __shfl_xor(l, 16);
  l = l + __shfl_xor(l, 32);
  if (g == 0) lpart[row * (size_t)pstride + c] = l;
}

// ---- pass 2: recompute QK^T, p = exp(s)/l, write attn, accumulate PV.
// LDS-staged K and V, double-buffered, register prefetch (T14 split).
// bm32/lpart/ctxpart/attn NOT __restrict__ (fallback-path aliasing).
__global__ __launch_bounds__(256, 6) void attn_out_kernel(
    const float* __restrict__ Q, const float* __restrict__ K,
    const float* __restrict__ V, const unsigned int* bm32,
    const float* lpart, int pstride, int np,
    float* ctxpart, float* attn, int nchunks) {
  __shared__ __align__(16) char Kl[2][KT * 128];
  __shared__ __align__(16) char Vl[2][KT * 128];
  const int tid  = threadIdx.x;
  const int lane = tid & 63, wv = tid >> 6;
  const int qr   = lane & 15, g = lane >> 4;
  const int bh   = blockIdx.y, c = blockIdx.z;
  const int q0blk = blockIdx.x * 64 + wv * 16;
  const int q    = q0blk + qr;
  const int CS   = SN / nchunks, kbeg = c * CS, NT = CS / KT;
  const size_t base = (size_t)bh * (SN * DN);
  const float *Kc = K + base, *Vc = V + base;
  const int sr = tid >> 4, sc = (tid & 15) * 4;

  const float* qrow = Q + base + (size_t)q * DN;
  bf16x8_t qf0 = load8bf(qrow + 8 * g);
  bf16x8_t qf1 = load8bf(qrow + 32 + 8 * g);
  const size_t row = (size_t)bh * SN + q;
  const unsigned int* bmrow = bm32 + row * (SN / 32);

  float l = 0.f;
  for (int i = 0; i < np; ++i) l += lpart[row * (size_t)pstride + i];
  const float rl = 1.0f / l;
  float* arow = attn + row * SN;

  f32x4 c0 = {0,0,0,0}, c1 = {0,0,0,0}, c2 = {0,0,0,0}, c3 = {0,0,0,0};

  f32x4 gk0 = *(const f32x4*)(Kc + (size_t)(kbeg + sr) * DN + sc);
  f32x4 gk1 = *(const f32x4*)(Kc + (size_t)(kbeg + sr + 16) * DN + sc);
  f32x4 gv0 = *(const f32x4*)(Vc + (size_t)(kbeg + sr) * DN + sc);
  f32x4 gv1 = *(const f32x4*)(Vc + (size_t)(kbeg + sr + 16) * DN + sc);
  stage_put(Kl[0], tid, gk0, gk1);
  stage_put(Vl[0], tid, gv0, gv1);
  __syncthreads();

  for (int t = 0; t < NT; ++t) {
    const int kt = kbeg + t * KT;
    const bool pf = (t + 1 < NT);
    if (pf) {
      gk0 = *(const f32x4*)(Kc + (size_t)(kt + KT + sr) * DN + sc);
      gk1 = *(const f32x4*)(Kc + (size_t)(kt + KT + sr + 16) * DN + sc);
      gv0 = *(const f32x4*)(Vc + (size_t)(kt + KT + sr) * DN + sc);
      gv1 = *(const f32x4*)(Vc + (size_t)(kt + KT + sr + 16) * DN + sc);
    }
    const char* Kb = Kl[t & 1];
    const char* Vb = Vl[t & 1];
    const unsigned int bmw = bmrow[kt >> 5];
    #pragma unroll
    for (int s = 0; s < 2; ++s) {
      const int kl = s * 16;
      const int rk = kl + qr;
      bf16x8_t kf0 = *(const bf16x8_t*)&Kb[swzoff(rk, 16 * g)];
      bf16x8_t kf1 = *(const bf16x8_t*)&Kb[swzoff(rk, 64 + 16 * g)];
      f32x4 acc = {0.f, 0.f, 0.f, 0.f};
      qk2_mfma(acc, kf0, qf0, kf1, qf1);
      // V fragments from LDS (16x16x16 B-layout: col qr+16j, k = 4g+e)
      bf16x4_t vf0, vf1, vf2, vf3;
      #pragma unroll
      for (int e = 0; e < 4; ++e) {
        const int rv = kl + 4 * g + e;
        vf0[e] = *(const __bf16*)&Vb[swzoff(rv, (qr     ) * 2)];
        vf1[e] = *(const __bf16*)&Vb[swzoff(rv, (qr + 16) * 2)];
        vf2[e] = *(const __bf16*)&Vb[swzoff(rv, (qr + 32) * 2)];
        vf3[e] = *(const __bf16*)&Vb[swzoff(rv, (qr + 48) * 2)];
      }
      const int sh = kl + 4 * g;
      float p0 = (((bmw >> (sh + 0)) & 1u) ? 0.f : __expf(acc[0] * SCL)) * rl;
      float p1 = (((bmw >> (sh + 1)) & 1u) ? 0.f : __expf(acc[1] * SCL)) * rl;
      float p2 = (((bmw >> (sh + 2)) & 1u) ? 0.f : __expf(acc[2] * SCL)) * rl;
      float p3 = (((bmw >> (sh + 3)) & 1u) ? 0.f : __expf(acc[3] * SCL)) * rl;
      __builtin_nontemporal_store((f32x4){p0, p1, p2, p3},
                                  (f32x4*)(arow + kt + kl + 4 * g));
      bf16x4_t pa = {(__bf16)p0, (__bf16)p1, (__bf16)p2, (__bf16)p3};
      pv4_mfma(c0, c1, c2, c3, pa, vf0, vf1, vf2, vf3);
    }
    if (pf) {
      stage_put(Kl[(t + 1) & 1], tid, gk0, gk1);
      stage_put(Vl[(t + 1) & 1], tid, gv0, gv1);
    }
    __syncthreads();
  }
  // ctx D-layout: col dv = lane&15 (+16*tile), row q = 4*(lane>>4)+reg
  float* cdst = ctxpart + (size_t)c * CTXN;
  #pragma unroll
  for (int j = 0; j < 4; ++j) {
    const size_t r = base + (size_t)(q0blk + 4 * g + j) * DN + qr;
    cdst[r +  0] = c0[j];
    cdst[r + 16] = c1[j];
    cdst[r + 32] = c2[j];
    cdst[r + 48] = c3[j];
  }
}

// ---- FAST path: sum the NK2 partial contexts.
__global__ __launch_bounds__(256) void ctx_reduce_kernel(
    const float* __restrict__ part, float* __restrict__ ctx) {
  const size_t i = ((size_t)blockIdx.x * blockDim.x + threadIdx.x) * 4;
  if (i >= CTXN) return;
  f32x4 s = *(const f32x4*)(part + i);
  s += *(const f32x4*)(part + CTXN + i);
  s += *(const f32x4*)(part + 2 * CTXN + i);
  s += *(const f32x4*)(part + 3 * CTXN + i);
  __builtin_nontemporal_store(s, (f32x4*)(ctx + i));
}

extern "C" void kernel_launch(void* const* d_in, const int* in_sizes, int n_in,
                              void* d_out, int out_size, void* d_ws, size_t ws_size,
                              hipStream_t stream) {
  const float* Q = (const float*)d_in[0];
  const float* K = (const float*)d_in[1];
  const float* V = (const float*)d_in[2];
  const unsigned int* mraw = (const unsigned int*)d_in[3];

  float* out  = (float*)d_out;
  float* ctx  = out;                 // CTXN f32 (8 MB)
  float* attn = out + CTXN;          // 67,108,864 f32

  char* wsb = (char*)d_ws;
  unsigned int* flag = (unsigned int*)wsb;

  const size_t BMB = (size_t)BHN * SN * (SN / 8);           // 8,388,608 B
  const size_t LPB = (size_t)BHN * SN * NK1 * sizeof(float);// 524,288 B
  const size_t CPB = (size_t)NK2 * CTXN * sizeof(float);    // 33,554,432 B
  const size_t off_bm = 256;
  const size_t off_lp = off_bm + BMB;
  const size_t off_cp = off_lp + LPB;

  const bool fast = ws_size >= off_cp + CPB;                // ~42.5 MB
  const bool mid  = !fast && ws_size >= off_lp + LPB;       // ~9 MB

  detect_mask_kernel<<<1, 64, 0, stream>>>(mraw, flag);

  dim3 grid1(SN / 64, BHN, NK1);
  if (fast) {
    unsigned long long* bm = (unsigned long long*)(wsb + off_bm);
    float* lp = (float*)(wsb + off_lp);
    float* cp = (float*)(wsb + off_cp);
    pack_mask_kernel<<<2048, 256, 0, stream>>>(mraw, bm, flag);
    attn_l_kernel<<<grid1, 256, 0, stream>>>(Q, K, (const unsigned int*)bm, lp, NK1, NK1);
    dim3 grid2(SN / 64, BHN, NK2);
    attn_out_kernel<<<grid2, 256, 0, stream>>>(Q, K, V, (const unsigned int*)bm,
                                               lp, NK1, NK1, cp, attn, NK2);
    ctx_reduce_kernel<<<(unsigned)(CTXN / 4 / 256), 256, 0, stream>>>(cp, ctx);
  } else if (mid) {
    unsigned long long* bm = (unsigned long long*)(wsb + off_bm);
    float* lp = (float*)(wsb + off_lp);
    pack_mask_kernel<<<2048, 256, 0, stream>>>(mraw, bm, flag);
    attn_l_kernel<<<grid1, 256, 0, stream>>>(Q, K, (const unsigned int*)bm, lp, NK1, NK1);
    dim3 grid2(SN / 64, BHN, 1);
    attn_out_kernel<<<grid2, 256, 0, stream>>>(Q, K, V, (const unsigned int*)bm,
                                               lp, NK1, NK1, ctx, attn, 1);
  } else {
    // FALLBACK: bitmask overlays ctx region; l-partials live in attn row
    // slots [0..NK1). Per-wave/row-exclusive ordering keeps overlays safe.
    unsigned long long* bm = (unsigned long long*)ctx;
    pack_mask_kernel<<<2048, 256, 0, stream>>>(mraw, bm, flag);
    attn_l_kernel<<<grid1, 256, 0, stream>>>(Q, K, (const unsigned int*)bm, attn, SN, NK1);
    dim3 grid2(SN / 64, BHN, 1);
    attn_out_kernel<<<grid2, 256, 0, stream>>>(Q, K, V, (const unsigned int*)bm,
                                               attn, SN, NK1, ctx, attn, 1);
  }
}

// Round 5
// 325.513 us; speedup vs baseline: 1.4764x; 1.4764x over previous
//
#include <hip/hip_runtime.h>

typedef float f32x4 __attribute__((ext_vector_type(4)));
typedef _Float16 f16x4 __attribute__((ext_vector_type(4)));
typedef __bf16 bf16x8_t __attribute__((ext_vector_type(8)));
typedef __bf16 bf16x4_t __attribute__((ext_vector_type(4)));

#define DEVFN static __device__ __forceinline__

constexpr int BHN = 16;    // B*H
constexpr int SN  = 2048;
constexpr int DN  = 64;
constexpr size_t CTXN = (size_t)BHN * SN * DN;   // 2,097,152
constexpr int NK1 = 4;    // k-split, pass 1
constexpr int NK2 = 4;    // k-split, pass 2

// ---- MFMA asm with internal hazard fencing (discipline verified R2/R3):
// s_nop 3 entry (VALU-write -> MFMA-read), s_nop 7 x2 exit (MFMA-write -> read).
DEVFN void qk2_mfma(f32x4& d, bf16x8_t a0, bf16x8_t b0, bf16x8_t a1, bf16x8_t b1) {
  asm volatile("s_nop 3\n\t"
               "v_mfma_f32_16x16x32_bf16 %0, %1, %2, %0\n\t"
               "v_mfma_f32_16x16x32_bf16 %0, %3, %4, %0\n\t"
               "s_nop 7\n\ts_nop 7"
               : "+v"(d) : "v"(a0), "v"(b0), "v"(a1), "v"(b1));
}

// dA += k0*qA0 + k1*qA1 ; dB += k0*qB0 + k1*qB1  (interleaved for pipe overlap)
DEVFN void qk4_mfma(f32x4& dA, f32x4& dB, bf16x8_t k0v, bf16x8_t k1v,
                    bf16x8_t qA0, bf16x8_t qA1, bf16x8_t qB0, bf16x8_t qB1) {
  asm volatile("s_nop 3\n\t"
               "v_mfma_f32_16x16x32_bf16 %0, %2, %4, %0\n\t"
               "v_mfma_f32_16x16x32_bf16 %1, %2, %6, %1\n\t"
               "v_mfma_f32_16x16x32_bf16 %0, %3, %5, %0\n\t"
               "v_mfma_f32_16x16x32_bf16 %1, %3, %7, %1\n\t"
               "s_nop 7\n\ts_nop 7"
               : "+v"(dA), "+v"(dB)
               : "v"(k0v), "v"(k1v), "v"(qA0), "v"(qA1), "v"(qB0), "v"(qB1));
}

// 8 independent accumulators: cA_j += paA*v_j, cB_j += paB*v_j
DEVFN void pv8_mfma(f32x4& a0, f32x4& a1, f32x4& a2, f32x4& a3,
                    f32x4& b0, f32x4& b1, f32x4& b2, f32x4& b3,
                    bf16x4_t paA, bf16x4_t paB,
                    bf16x4_t v0, bf16x4_t v1, bf16x4_t v2, bf16x4_t v3) {
  asm volatile("s_nop 3\n\t"
               "v_mfma_f32_16x16x16_bf16 %0, %8, %10, %0\n\t"
               "v_mfma_f32_16x16x16_bf16 %4, %9, %10, %4\n\t"
               "v_mfma_f32_16x16x16_bf16 %1, %8, %11, %1\n\t"
               "v_mfma_f32_16x16x16_bf16 %5, %9, %11, %5\n\t"
               "v_mfma_f32_16x16x16_bf16 %2, %8, %12, %2\n\t"
               "v_mfma_f32_16x16x16_bf16 %6, %9, %12, %6\n\t"
               "v_mfma_f32_16x16x16_bf16 %3, %8, %13, %3\n\t"
               "v_mfma_f32_16x16x16_bf16 %7, %9, %13, %7\n\t"
               "s_nop 7\n\ts_nop 7"
               : "+v"(a0), "+v"(a1), "+v"(a2), "+v"(a3),
                 "+v"(b0), "+v"(b1), "+v"(b2), "+v"(b3)
               : "v"(paA), "v"(paB), "v"(v0), "v"(v1), "v"(v2), "v"(v3));
}

// ---- detect mask storage width: fl==1 -> uint8 bytes; else 4-byte words.
__global__ void detect_mask_kernel(const unsigned int* __restrict__ mraw,
                                   unsigned int* __restrict__ flag) {
  unsigned int f = 0;
  for (int i = threadIdx.x; i < 4096; i += 64) {
    unsigned int w = mraw[i];
    if (w == 0x3F800000u) f |= 2u;
    else if (w > 1u) f |= 1u;
  }
  unsigned long long b2 = __ballot((f & 2u) != 0u);
  unsigned long long b1 = __ballot((f & 1u) != 0u);
  if (threadIdx.x == 0) *flag = b2 ? 2u : (b1 ? 1u : 0u);
}

// ---- pack mask -> bitmask (bit=1 means masked), coalesced wave-ballot.
__global__ __launch_bounds__(256) void pack_mask_kernel(
    const unsigned int* __restrict__ mraw, unsigned long long* __restrict__ bm,
    const unsigned int* __restrict__ flag) {
  const int lane = threadIdx.x & 63;
  const int wid  = blockIdx.x * (blockDim.x >> 6) + (threadIdx.x >> 6);
  const int nw   = gridDim.x * (blockDim.x >> 6);
  if (*flag != 1u) {
    const int W = BHN * SN * (SN / 64);          // 1,048,576
    for (int w = wid; w < W; w += nw) {
      unsigned int v = __builtin_nontemporal_load(mraw + (size_t)w * 64 + lane);
      unsigned long long bits = __ballot(v != 0u);
      if (lane == 0) bm[w] = bits;
    }
  } else {
    const int W = BHN * SN * (SN / 256);         // 262,144
    for (int w = wid; w < W; w += nw) {
      unsigned int v = __builtin_nontemporal_load(mraw + (size_t)w * 64 + lane);
      #pragma unroll
      for (int b = 0; b < 4; ++b) {
        unsigned long long bits = __ballot(((v >> (8 * b)) & 0xFFu) != 0u);
        if (lane == 0) bm[(size_t)w * 4 + b] = bits;
      }
    }
  }
}

// ---- f32 -> bf16 elementwise convert (scale folded; 0.125 is exact in bf16).
__global__ __launch_bounds__(256) void conv_bf16_kernel(
    const float* __restrict__ src, __bf16* __restrict__ dst, float scale) {
  const size_t i = ((size_t)blockIdx.x * 256 + threadIdx.x) * 4;
  f32x4 v = *(const f32x4*)(src + i);
  bf16x4_t o = {(__bf16)(v[0] * scale), (__bf16)(v[1] * scale),
                (__bf16)(v[2] * scale), (__bf16)(v[3] * scale)};
  *(bf16x4_t*)(dst + i) = o;
}

// ---- V[k][d] f32 -> Vt[d][k] bf16. Wave handles 32k x 64d: 32 coalesced
// row-reads (lane = d), per-lane 64B contiguous store into row d.
__global__ __launch_bounds__(256) void conv_vt_kernel(
    const float* __restrict__ V, __bf16* __restrict__ Vt) {
  const int lane = threadIdx.x & 63, wv = threadIdx.x >> 6;
  const int k0 = (blockIdx.x * 4 + wv) * 32;
  const int bh = blockIdx.y;
  const float* src = V + (size_t)bh * SN * DN;
  __bf16* dst = Vt + (size_t)bh * DN * SN + (size_t)lane * SN + k0;
  bf16x8_t w0, w1, w2, w3;
  #pragma unroll
  for (int i = 0; i < 8; ++i) {
    w0[i] = (__bf16)src[(size_t)(k0 + i) * DN + lane];
    w1[i] = (__bf16)src[(size_t)(k0 + 8 + i) * DN + lane];
    w2[i] = (__bf16)src[(size_t)(k0 + 16 + i) * DN + lane];
    w3[i] = (__bf16)src[(size_t)(k0 + 24 + i) * DN + lane];
  }
  *(bf16x8_t*)(dst)      = w0;
  *(bf16x8_t*)(dst + 8)  = w1;
  *(bf16x8_t*)(dst + 16) = w2;
  *(bf16x8_t*)(dst + 24) = w3;
}

// ---- pass 1: l-partials. Swapped QK^T (x32 D-layout: q=lane&15, k=4g+reg),
// bf16 pre-scaled K -> s = acc directly. Register prefetch of next K frags.
__global__ __launch_bounds__(256, 8) void attn_l_kernel(
    const __bf16* __restrict__ Qb, const __bf16* __restrict__ Kb,
    const unsigned int* __restrict__ bm32, float* __restrict__ lpart) {
  const int lane = threadIdx.x & 63, wv = threadIdx.x >> 6;
  const int qr = lane & 15, g = lane >> 4;
  const int bh = blockIdx.y, c = blockIdx.z;
  const int q = blockIdx.x * 64 + wv * 16 + qr;
  const int CS = SN / NK1, kbeg = c * CS;
  const __bf16* Qbb = Qb + (size_t)bh * SN * DN;
  const __bf16* Kbb = Kb + (size_t)bh * SN * DN;
  bf16x8_t qf0 = *(const bf16x8_t*)(Qbb + (size_t)q * DN + 8 * g);
  bf16x8_t qf1 = *(const bf16x8_t*)(Qbb + (size_t)q * DN + 32 + 8 * g);
  const size_t row = (size_t)bh * SN + q;
  const unsigned int* bmrow = bm32 + row * (SN / 32);

  bf16x8_t kf0 = *(const bf16x8_t*)(Kbb + (size_t)(kbeg + qr) * DN + 8 * g);
  bf16x8_t kf1 = *(const bf16x8_t*)(Kbb + (size_t)(kbeg + qr) * DN + 32 + 8 * g);
  float l = 0.f;
  #pragma unroll 2
  for (int t = 0; t < CS / 16; ++t) {
    const int kt = kbeg + t * 16;
    const int kn = kbeg + ((t + 1) & (CS / 16 - 1)) * 16;   // clamped wrap
    bf16x8_t nf0 = *(const bf16x8_t*)(Kbb + (size_t)(kn + qr) * DN + 8 * g);
    bf16x8_t nf1 = *(const bf16x8_t*)(Kbb + (size_t)(kn + qr) * DN + 32 + 8 * g);
    f32x4 acc = {0.f, 0.f, 0.f, 0.f};
    qk2_mfma(acc, kf0, qf0, kf1, qf1);
    const unsigned int bmw = bmrow[kt >> 5];
    const int sh = (kt & 16) + 4 * g;
    l += ((bmw >> (sh + 0)) & 1u) ? 0.f : __expf(acc[0]);
    l += ((bmw >> (sh + 1)) & 1u) ? 0.f : __expf(acc[1]);
    l += ((bmw >> (sh + 2)) & 1u) ? 0.f : __expf(acc[2]);
    l += ((bmw >> (sh + 3)) & 1u) ? 0.f : __expf(acc[3]);
    kf0 = nf0; kf1 = nf1;
  }
  l = l + __shfl_xor(l, 16);
  l = l + __shfl_xor(l, 32);
  if (g == 0) lpart[row * NK1 + c] = l;
}

// ---- pass 2: 2 q-tiles per wave (shared K/V frags, 2 independent chains).
// p in x32 D-layout == 16x16x16 A-layout (no shuffles). V from Vt via b64.
__global__ __launch_bounds__(256, 4) void attn_out_kernel(
    const __bf16* __restrict__ Qb, const __bf16* __restrict__ Kb,
    const __bf16* __restrict__ Vt, const unsigned int* __restrict__ bm32,
    const float* __restrict__ lpart, _Float16* __restrict__ cp,
    float* __restrict__ attn) {
  const int lane = threadIdx.x & 63, wv = threadIdx.x >> 6;
  const int qr = lane & 15, g = lane >> 4;
  const int bh = blockIdx.y, c = blockIdx.z;
  const int q0 = blockIdx.x * 128 + wv * 32;
  const int CS = SN / NK2, kbeg = c * CS;
  const __bf16* Qbb = Qb + (size_t)bh * SN * DN;
  const __bf16* Kbb = Kb + (size_t)bh * SN * DN;
  const __bf16* Vtb = Vt + (size_t)bh * DN * SN;
  const int qA = q0 + qr, qB = q0 + 16 + qr;
  bf16x8_t qfA0 = *(const bf16x8_t*)(Qbb + (size_t)qA * DN + 8 * g);
  bf16x8_t qfA1 = *(const bf16x8_t*)(Qbb + (size_t)qA * DN + 32 + 8 * g);
  bf16x8_t qfB0 = *(const bf16x8_t*)(Qbb + (size_t)qB * DN + 8 * g);
  bf16x8_t qfB1 = *(const bf16x8_t*)(Qbb + (size_t)qB * DN + 32 + 8 * g);
  const size_t rowA = (size_t)bh * SN + qA;
  const size_t rowB = (size_t)bh * SN + qB;
  f32x4 l4A = *(const f32x4*)(lpart + rowA * NK1);
  f32x4 l4B = *(const f32x4*)(lpart + rowB * NK1);
  const float rlA = 1.0f / (l4A[0] + l4A[1] + l4A[2] + l4A[3]);
  const float rlB = 1.0f / (l4B[0] + l4B[1] + l4B[2] + l4B[3]);
  const unsigned int* bmrA = bm32 + rowA * (SN / 32);
  const unsigned int* bmrB = bm32 + rowB * (SN / 32);
  float* arowA = attn + rowA * SN;
  float* arowB = attn + rowB * SN;

  f32x4 cA0 = {0,0,0,0}, cA1 = {0,0,0,0}, cA2 = {0,0,0,0}, cA3 = {0,0,0,0};
  f32x4 cB0 = {0,0,0,0}, cB1 = {0,0,0,0}, cB2 = {0,0,0,0}, cB3 = {0,0,0,0};

  bf16x8_t kf0 = *(const bf16x8_t*)(Kbb + (size_t)(kbeg + qr) * DN + 8 * g);
  bf16x8_t kf1 = *(const bf16x8_t*)(Kbb + (size_t)(kbeg + qr) * DN + 32 + 8 * g);
  bf16x4_t vf0 = *(const bf16x4_t*)(Vtb + (size_t)(qr     ) * SN + kbeg + 4 * g);
  bf16x4_t vf1 = *(const bf16x4_t*)(Vtb + (size_t)(qr + 16) * SN + kbeg + 4 * g);
  bf16x4_t vf2 = *(const bf16x4_t*)(Vtb + (size_t)(qr + 32) * SN + kbeg + 4 * g);
  bf16x4_t vf3 = *(const bf16x4_t*)(Vtb + (size_t)(qr + 48) * SN + kbeg + 4 * g);

  #pragma unroll 2
  for (int t = 0; t < CS / 16; ++t) {
    const int kt = kbeg + t * 16;
    const int kn = kbeg + ((t + 1) & (CS / 16 - 1)) * 16;   // clamped wrap
    bf16x8_t nk0 = *(const bf16x8_t*)(Kbb + (size_t)(kn + qr) * DN + 8 * g);
    bf16x8_t nk1 = *(const bf16x8_t*)(Kbb + (size_t)(kn + qr) * DN + 32 + 8 * g);
    bf16x4_t nv0 = *(const bf16x4_t*)(Vtb + (size_t)(qr     ) * SN + kn + 4 * g);
    bf16x4_t nv1 = *(const bf16x4_t*)(Vtb + (size_t)(qr + 16) * SN + kn + 4 * g);
    bf16x4_t nv2 = *(const bf16x4_t*)(Vtb + (size_t)(qr + 32) * SN + kn + 4 * g);
    bf16x4_t nv3 = *(const bf16x4_t*)(Vtb + (size_t)(qr + 48) * SN + kn + 4 * g);
    f32x4 aA = {0,0,0,0}, aB = {0,0,0,0};
    qk4_mfma(aA, aB, kf0, kf1, qfA0, qfA1, qfB0, qfB1);
    const unsigned int bmwA = bmrA[kt >> 5];
    const unsigned int bmwB = bmrB[kt >> 5];
    const int sh = (kt & 16) + 4 * g;
    float pA0 = (((bmwA >> (sh + 0)) & 1u) ? 0.f : __expf(aA[0])) * rlA;
    float pA1 = (((bmwA >> (sh + 1)) & 1u) ? 0.f : __expf(aA[1])) * rlA;
    float pA2 = (((bmwA >> (sh + 2)) & 1u) ? 0.f : __expf(aA[2])) * rlA;
    float pA3 = (((bmwA >> (sh + 3)) & 1u) ? 0.f : __expf(aA[3])) * rlA;
    float pB0 = (((bmwB >> (sh + 0)) & 1u) ? 0.f : __expf(aB[0])) * rlB;
    float pB1 = (((bmwB >> (sh + 1)) & 1u) ? 0.f : __expf(aB[1])) * rlB;
    float pB2 = (((bmwB >> (sh + 2)) & 1u) ? 0.f : __expf(aB[2])) * rlB;
    float pB3 = (((bmwB >> (sh + 3)) & 1u) ? 0.f : __expf(aB[3])) * rlB;
    __builtin_nontemporal_store((f32x4){pA0, pA1, pA2, pA3},
                                (f32x4*)(arowA + kt + 4 * g));
    __builtin_nontemporal_store((f32x4){pB0, pB1, pB2, pB3},
                                (f32x4*)(arowB + kt + 4 * g));
    bf16x4_t paA = {(__bf16)pA0, (__bf16)pA1, (__bf16)pA2, (__bf16)pA3};
    bf16x4_t paB = {(__bf16)pB0, (__bf16)pB1, (__bf16)pB2, (__bf16)pB3};
    pv8_mfma(cA0, cA1, cA2, cA3, cB0, cB1, cB2, cB3, paA, paB, vf0, vf1, vf2, vf3);
    kf0 = nk0; kf1 = nk1;
    vf0 = nv0; vf1 = nv1; vf2 = nv2; vf3 = nv3;
  }
  // ctx partial (f16): D-layout col dv = qr (+16*tile), row q = 4g+reg
  _Float16* cdst = cp + (size_t)c * CTXN;
  const size_t baseo = (size_t)bh * SN * DN;
  #pragma unroll
  for (int j = 0; j < 4; ++j) {
    const size_t rA = baseo + (size_t)(q0 + 4 * g + j) * DN + qr;
    const size_t rB = baseo + (size_t)(q0 + 16 + 4 * g + j) * DN + qr;
    cdst[rA]      = (_Float16)cA0[j];
    cdst[rA + 16] = (_Float16)cA1[j];
    cdst[rA + 32] = (_Float16)cA2[j];
    cdst[rA + 48] = (_Float16)cA3[j];
    cdst[rB]      = (_Float16)cB0[j];
    cdst[rB + 16] = (_Float16)cB1[j];
    cdst[rB + 32] = (_Float16)cB2[j];
    cdst[rB + 48] = (_Float16)cB3[j];
  }
}

// ---- sum the NK2 f16 partial contexts -> f32 ctx.
__global__ __launch_bounds__(256) void ctx_reduce_kernel(
    const _Float16* __restrict__ cp, float* __restrict__ ctx) {
  const size_t i = ((size_t)blockIdx.x * 256 + threadIdx.x) * 4;
  f16x4 a = *(const f16x4*)(cp + i);
  f16x4 b = *(const f16x4*)(cp + CTXN + i);
  f16x4 d = *(const f16x4*)(cp + 2 * CTXN + i);
  f16x4 e = *(const f16x4*)(cp + 3 * CTXN + i);
  f32x4 s;
  #pragma unroll
  for (int k = 0; k < 4; ++k)
    s[k] = ((float)a[k] + (float)b[k]) + ((float)d[k] + (float)e[k]);
  __builtin_nontemporal_store(s, (f32x4*)(ctx + i));
}

extern "C" void kernel_launch(void* const* d_in, const int* in_sizes, int n_in,
                              void* d_out, int out_size, void* d_ws, size_t ws_size,
                              hipStream_t stream) {
  const float* Q = (const float*)d_in[0];
  const float* K = (const float*)d_in[1];
  const float* V = (const float*)d_in[2];
  const unsigned int* mraw = (const unsigned int*)d_in[3];

  float* out  = (float*)d_out;
  float* ctx  = out;                 // CTXN f32
  float* attn = out + CTXN;          // 67,108,864 f32

  // ws layout (total 38.3 MB; R3/R4's 56% occupancy proved ws >= 42.4 MB):
  char* wsb = (char*)d_ws;
  unsigned int* flag = (unsigned int*)wsb;                       // 256 B
  unsigned long long* bm = (unsigned long long*)(wsb + 256);     // 8 MB
  float* lp   = (float*)(wsb + 256 + 8388608);                   // 512 KB
  __bf16* Qb  = (__bf16*)(wsb + 256 + 8388608 + 524288);         // 4 MB
  __bf16* Kb  = (__bf16*)(wsb + 256 + 8388608 + 524288 + 4194304);
  __bf16* Vt  = (__bf16*)(wsb + 256 + 8388608 + 524288 + 2 * 4194304);
  _Float16* cp = (_Float16*)(wsb + 256 + 8388608 + 524288 + 3 * 4194304); // 16 MB
  const unsigned int* bm32 = (const unsigned int*)bm;

  detect_mask_kernel<<<1, 64, 0, stream>>>(mraw, flag);
  pack_mask_kernel<<<2048, 256, 0, stream>>>(mraw, bm, flag);
  conv_bf16_kernel<<<2048, 256, 0, stream>>>(Q, Qb, 1.0f);
  conv_bf16_kernel<<<2048, 256, 0, stream>>>(K, Kb, 0.125f);  // fold 1/sqrt(64)
  conv_vt_kernel<<<dim3(16, BHN), 256, 0, stream>>>(V, Vt);

  attn_l_kernel<<<dim3(SN / 64, BHN, NK1), 256, 0, stream>>>(Qb, Kb, bm32, lp);
  attn_out_kernel<<<dim3(SN / 128, BHN, NK2), 256, 0, stream>>>(Qb, Kb, Vt, bm32,
                                                                lp, cp, attn);
  ctx_reduce_kernel<<<2048, 256, 0, stream>>>(cp, ctx);
}

// Round 6
// 298.454 us; speedup vs baseline: 1.6103x; 1.0907x over previous
//
#include <hip/hip_runtime.h>

typedef float f32x4 __attribute__((ext_vector_type(4)));
typedef _Float16 f16x4 __attribute__((ext_vector_type(4)));
typedef unsigned int u32x4 __attribute__((ext_vector_type(4)));
typedef __bf16 bf16x8_t __attribute__((ext_vector_type(8)));
typedef __bf16 bf16x4_t __attribute__((ext_vector_type(4)));

#define DEVFN static __device__ __forceinline__

constexpr int BHN = 16;    // B*H
constexpr int SN  = 2048;
constexpr int DN  = 64;
constexpr size_t CTXN = (size_t)BHN * SN * DN;   // 2,097,152
constexpr int NK1 = 4;    // k-split, pass 1
constexpr int NK2 = 4;    // k-split, pass 2

// ---- MFMA asm with internal hazard fencing (verified R2-R5).
DEVFN void qk4_mfma(f32x4& dA, f32x4& dB, bf16x8_t k0v, bf16x8_t k1v,
                    bf16x8_t qA0, bf16x8_t qA1, bf16x8_t qB0, bf16x8_t qB1) {
  asm volatile("s_nop 3\n\t"
               "v_mfma_f32_16x16x32_bf16 %0, %2, %4, %0\n\t"
               "v_mfma_f32_16x16x32_bf16 %1, %2, %6, %1\n\t"
               "v_mfma_f32_16x16x32_bf16 %0, %3, %5, %0\n\t"
               "v_mfma_f32_16x16x32_bf16 %1, %3, %7, %1\n\t"
               "s_nop 7\n\ts_nop 7"
               : "+v"(dA), "+v"(dB)
               : "v"(k0v), "v"(k1v), "v"(qA0), "v"(qA1), "v"(qB0), "v"(qB1));
}

DEVFN void pv8_mfma(f32x4& a0, f32x4& a1, f32x4& a2, f32x4& a3,
                    f32x4& b0, f32x4& b1, f32x4& b2, f32x4& b3,
                    bf16x4_t paA, bf16x4_t paB,
                    bf16x4_t v0, bf16x4_t v1, bf16x4_t v2, bf16x4_t v3) {
  asm volatile("s_nop 3\n\t"
               "v_mfma_f32_16x16x16_bf16 %0, %8, %10, %0\n\t"
               "v_mfma_f32_16x16x16_bf16 %4, %9, %10, %4\n\t"
               "v_mfma_f32_16x16x16_bf16 %1, %8, %11, %1\n\t"
               "v_mfma_f32_16x16x16_bf16 %5, %9, %11, %5\n\t"
               "v_mfma_f32_16x16x16_bf16 %2, %8, %12, %2\n\t"
               "v_mfma_f32_16x16x16_bf16 %6, %9, %12, %6\n\t"
               "v_mfma_f32_16x16x16_bf16 %3, %8, %13, %3\n\t"
               "v_mfma_f32_16x16x16_bf16 %7, %9, %13, %7\n\t"
               "s_nop 7\n\ts_nop 7"
               : "+v"(a0), "+v"(a1), "+v"(a2), "+v"(a3),
                 "+v"(b0), "+v"(b1), "+v"(b2), "+v"(b3)
               : "v"(paA), "v"(paB), "v"(v0), "v"(v1), "v"(v2), "v"(v3));
}

// ---- detect mask storage width: fl==1 -> uint8 bytes; else 4-byte words.
__global__ void detect_mask_kernel(const unsigned int* __restrict__ mraw,
                                   unsigned int* __restrict__ flag) {
  unsigned int f = 0;
  for (int i = threadIdx.x; i < 4096; i += 64) {
    unsigned int w = mraw[i];
    if (w == 0x3F800000u) f |= 2u;
    else if (w > 1u) f |= 1u;
  }
  unsigned long long b2 = __ballot((f & 2u) != 0u);
  unsigned long long b1 = __ballot((f & 1u) != 0u);
  if (threadIdx.x == 0) *flag = b2 ? 2u : (b1 ? 1u : 0u);
}

// ---- pack mask -> TRANSPOSED bitmask bmT[bh][k/32][q] (bit j = k%32).
// Reads are 128 B/lane per output word (full-line efficient); writes are
// fully coalesced (consecutive q = consecutive lanes).
__global__ __launch_bounds__(256) void pack_mask_T_kernel(
    const void* __restrict__ mraw, unsigned int* __restrict__ bmT,
    const unsigned int* __restrict__ flag) {
  const unsigned int fl = *flag;
  const int tid = blockIdx.x * 256 + threadIdx.x;
  const int NT  = gridDim.x * 256;
  if (fl != 1u) {
    // 4-byte elements: one u32 word per (bh, kc2, q)
    const int W = BHN * (SN / 32) * SN;          // 2,097,152
    const unsigned int* m32 = (const unsigned int*)mraw;
    for (int w = tid; w < W; w += NT) {
      const int q   = w & (SN - 1);
      const int kc2 = (w >> 11) & (SN / 32 - 1);
      const int bh  = w >> 17;
      const unsigned int* src = m32 + ((size_t)(bh * SN + q) * SN) + kc2 * 32;
      unsigned int r = 0;
      #pragma unroll
      for (int j = 0; j < 8; ++j) {
        u32x4 v = *(const u32x4*)(src + j * 4);
        r |= ((unsigned)(v[0] != 0u)) << (4 * j)
           | ((unsigned)(v[1] != 0u)) << (4 * j + 1)
           | ((unsigned)(v[2] != 0u)) << (4 * j + 2)
           | ((unsigned)(v[3] != 0u)) << (4 * j + 3);
      }
      bmT[w] = r;
    }
  } else {
    // 1-byte elements: lane builds 4 words from 128 consecutive bytes
    const int W4 = BHN * (SN / 128) * SN;        // 524,288
    const unsigned char* m8 = (const unsigned char*)mraw;
    for (int w4 = tid; w4 < W4; w4 += NT) {
      const int q   = w4 & (SN - 1);
      const int kc8 = (w4 >> 11) & (SN / 128 - 1);
      const int bh  = w4 >> 15;
      const unsigned char* src = m8 + ((size_t)(bh * SN + q) * SN) + kc8 * 128;
      #pragma unroll
      for (int i = 0; i < 4; ++i) {
        const unsigned int* s32 = (const unsigned int*)(src + 32 * i);
        unsigned int r = 0;
        #pragma unroll
        for (int j = 0; j < 8; ++j) {
          unsigned int x = s32[j];
          r |= ((unsigned)((x & 0x000000FFu) != 0u)) << (4 * j)
             | ((unsigned)((x & 0x0000FF00u) != 0u)) << (4 * j + 1)
             | ((unsigned)((x & 0x00FF0000u) != 0u)) << (4 * j + 2)
             | ((unsigned)((x & 0xFF000000u) != 0u)) << (4 * j + 3);
        }
        bmT[((size_t)(bh * (SN / 32) + kc8 * 4 + i)) * SN + q] = r;
      }
    }
  }
}

// ---- f32 -> bf16 convert; z=0: Q (scale 1), z=1: K (scale 0.125, exact).
__global__ __launch_bounds__(256) void conv_qk_kernel(
    const float* __restrict__ Q, const float* __restrict__ K,
    __bf16* __restrict__ Qb, __bf16* __restrict__ Kb) {
  const size_t i = ((size_t)blockIdx.x * 256 + threadIdx.x) * 4;
  const float* src = blockIdx.y ? K : Q;
  __bf16* dst = blockIdx.y ? Kb : Qb;
  const float scale = blockIdx.y ? 0.125f : 1.0f;
  f32x4 v = *(const f32x4*)(src + i);
  bf16x4_t o = {(__bf16)(v[0] * scale), (__bf16)(v[1] * scale),
                (__bf16)(v[2] * scale), (__bf16)(v[3] * scale)};
  *(bf16x4_t*)(dst + i) = o;
}

// ---- V[k][d] f32 -> Vt[d][k] bf16 (coalesced reads, per-lane 64B stores).
__global__ __launch_bounds__(256) void conv_vt_kernel(
    const float* __restrict__ V, __bf16* __restrict__ Vt) {
  const int lane = threadIdx.x & 63, wv = threadIdx.x >> 6;
  const int k0 = (blockIdx.x * 4 + wv) * 32;
  const int bh = blockIdx.y;
  const float* src = V + (size_t)bh * SN * DN;
  __bf16* dst = Vt + (size_t)bh * DN * SN + (size_t)lane * SN + k0;
  bf16x8_t w0, w1, w2, w3;
  #pragma unroll
  for (int i = 0; i < 8; ++i) {
    w0[i] = (__bf16)src[(size_t)(k0 + i) * DN + lane];
    w1[i] = (__bf16)src[(size_t)(k0 + 8 + i) * DN + lane];
    w2[i] = (__bf16)src[(size_t)(k0 + 16 + i) * DN + lane];
    w3[i] = (__bf16)src[(size_t)(k0 + 24 + i) * DN + lane];
  }
  *(bf16x8_t*)(dst)      = w0;
  *(bf16x8_t*)(dst + 8)  = w1;
  *(bf16x8_t*)(dst + 16) = w2;
  *(bf16x8_t*)(dst + 24) = w3;
}

// ---- pass 1: l-partials, 2 q-tiles/wave (shared K frags, 2x ILP).
__global__ __launch_bounds__(256, 4) void attn_l_kernel(
    const __bf16* __restrict__ Qb, const __bf16* __restrict__ Kb,
    const unsigned int* __restrict__ bmT, float* __restrict__ lpart) {
  const int lane = threadIdx.x & 63, wv = threadIdx.x >> 6;
  const int qr = lane & 15, g = lane >> 4;
  const int bh = blockIdx.y, c = blockIdx.z;
  const int q0 = blockIdx.x * 128 + wv * 32;
  const int CS = SN / NK1, kbeg = c * CS;
  const __bf16* Qbb = Qb + (size_t)bh * SN * DN;
  const __bf16* Kbb = Kb + (size_t)bh * SN * DN;
  const int qA = q0 + qr, qB = q0 + 16 + qr;
  bf16x8_t qfA0 = *(const bf16x8_t*)(Qbb + (size_t)qA * DN + 8 * g);
  bf16x8_t qfA1 = *(const bf16x8_t*)(Qbb + (size_t)qA * DN + 32 + 8 * g);
  bf16x8_t qfB0 = *(const bf16x8_t*)(Qbb + (size_t)qB * DN + 8 * g);
  bf16x8_t qfB1 = *(const bf16x8_t*)(Qbb + (size_t)qB * DN + 32 + 8 * g);
  const size_t rowA = (size_t)bh * SN + qA;
  const size_t rowB = (size_t)bh * SN + qB;
  const unsigned int* bmb = bmT + (size_t)bh * (SN / 32) * SN;

  bf16x8_t kf0 = *(const bf16x8_t*)(Kbb + (size_t)(kbeg + qr) * DN + 8 * g);
  bf16x8_t kf1 = *(const bf16x8_t*)(Kbb + (size_t)(kbeg + qr) * DN + 32 + 8 * g);
  float lA = 0.f, lB = 0.f;
  unsigned int wmA = 0, wmB = 0;
  #pragma unroll 2
  for (int t = 0; t < CS / 16; ++t) {
    const int kt = kbeg + t * 16;
    const int kn = kbeg + ((t + 1) & (CS / 16 - 1)) * 16;   // clamped wrap
    bf16x8_t nk0 = *(const bf16x8_t*)(Kbb + (size_t)(kn + qr) * DN + 8 * g);
    bf16x8_t nk1 = *(const bf16x8_t*)(Kbb + (size_t)(kn + qr) * DN + 32 + 8 * g);
    if ((t & 1) == 0) {
      wmA = bmb[(size_t)(kt >> 5) * SN + qA];
      wmB = bmb[(size_t)(kt >> 5) * SN + qB];
    }
    f32x4 aA = {0,0,0,0}, aB = {0,0,0,0};
    qk4_mfma(aA, aB, kf0, kf1, qfA0, qfA1, qfB0, qfB1);
    const int sh = (kt & 16) + 4 * g;
    lA += ((wmA >> (sh + 0)) & 1u) ? 0.f : __expf(aA[0]);
    lA += ((wmA >> (sh + 1)) & 1u) ? 0.f : __expf(aA[1]);
    lA += ((wmA >> (sh + 2)) & 1u) ? 0.f : __expf(aA[2]);
    lA += ((wmA >> (sh + 3)) & 1u) ? 0.f : __expf(aA[3]);
    lB += ((wmB >> (sh + 0)) & 1u) ? 0.f : __expf(aB[0]);
    lB += ((wmB >> (sh + 1)) & 1u) ? 0.f : __expf(aB[1]);
    lB += ((wmB >> (sh + 2)) & 1u) ? 0.f : __expf(aB[2]);
    lB += ((wmB >> (sh + 3)) & 1u) ? 0.f : __expf(aB[3]);
    kf0 = nk0; kf1 = nk1;
  }
  lA = lA + __shfl_xor(lA, 16); lA = lA + __shfl_xor(lA, 32);
  lB = lB + __shfl_xor(lB, 16); lB = lB + __shfl_xor(lB, 32);
  if (g == 0) {
    lpart[rowA * NK1 + c] = lA;
    lpart[rowB * NK1 + c] = lB;
  }
}

// ---- pass 2: recompute QK^T, p = exp(s)/l, write attn (PLAIN stores for
// L2 write-combining), accumulate PV. 2 q-tiles/wave.
__global__ __launch_bounds__(256, 4) void attn_out_kernel(
    const __bf16* __restrict__ Qb, const __bf16* __restrict__ Kb,
    const __bf16* __restrict__ Vt, const unsigned int* __restrict__ bmT,
    const float* __restrict__ lpart, _Float16* __restrict__ cp,
    float* __restrict__ attn) {
  const int lane = threadIdx.x & 63, wv = threadIdx.x >> 6;
  const int qr = lane & 15, g = lane >> 4;
  const int bh = blockIdx.y, c = blockIdx.z;
  const int q0 = blockIdx.x * 128 + wv * 32;
  const int CS = SN / NK2, kbeg = c * CS;
  const __bf16* Qbb = Qb + (size_t)bh * SN * DN;
  const __bf16* Kbb = Kb + (size_t)bh * SN * DN;
  const __bf16* Vtb = Vt + (size_t)bh * DN * SN;
  const int qA = q0 + qr, qB = q0 + 16 + qr;
  bf16x8_t qfA0 = *(const bf16x8_t*)(Qbb + (size_t)qA * DN + 8 * g);
  bf16x8_t qfA1 = *(const bf16x8_t*)(Qbb + (size_t)qA * DN + 32 + 8 * g);
  bf16x8_t qfB0 = *(const bf16x8_t*)(Qbb + (size_t)qB * DN + 8 * g);
  bf16x8_t qfB1 = *(const bf16x8_t*)(Qbb + (size_t)qB * DN + 32 + 8 * g);
  const size_t rowA = (size_t)bh * SN + qA;
  const size_t rowB = (size_t)bh * SN + qB;
  f32x4 l4A = *(const f32x4*)(lpart + rowA * NK1);
  f32x4 l4B = *(const f32x4*)(lpart + rowB * NK1);
  const float rlA = 1.0f / (l4A[0] + l4A[1] + l4A[2] + l4A[3]);
  const float rlB = 1.0f / (l4B[0] + l4B[1] + l4B[2] + l4B[3]);
  const unsigned int* bmb = bmT + (size_t)bh * (SN / 32) * SN;
  float* arowA = attn + rowA * SN;
  float* arowB = attn + rowB * SN;

  f32x4 cA0 = {0,0,0,0}, cA1 = {0,0,0,0}, cA2 = {0,0,0,0}, cA3 = {0,0,0,0};
  f32x4 cB0 = {0,0,0,0}, cB1 = {0,0,0,0}, cB2 = {0,0,0,0}, cB3 = {0,0,0,0};

  bf16x8_t kf0 = *(const bf16x8_t*)(Kbb + (size_t)(kbeg + qr) * DN + 8 * g);
  bf16x8_t kf1 = *(const bf16x8_t*)(Kbb + (size_t)(kbeg + qr) * DN + 32 + 8 * g);
  bf16x4_t vf0 = *(const bf16x4_t*)(Vtb + (size_t)(qr     ) * SN + kbeg + 4 * g);
  bf16x4_t vf1 = *(const bf16x4_t*)(Vtb + (size_t)(qr + 16) * SN + kbeg + 4 * g);
  bf16x4_t vf2 = *(const bf16x4_t*)(Vtb + (size_t)(qr + 32) * SN + kbeg + 4 * g);
  bf16x4_t vf3 = *(const bf16x4_t*)(Vtb + (size_t)(qr + 48) * SN + kbeg + 4 * g);
  unsigned int wmA = 0, wmB = 0;

  #pragma unroll 2
  for (int t = 0; t < CS / 16; ++t) {
    const int kt = kbeg + t * 16;
    const int kn = kbeg + ((t + 1) & (CS / 16 - 1)) * 16;   // clamped wrap
    bf16x8_t nk0 = *(const bf16x8_t*)(Kbb + (size_t)(kn + qr) * DN + 8 * g);
    bf16x8_t nk1 = *(const bf16x8_t*)(Kbb + (size_t)(kn + qr) * DN + 32 + 8 * g);
    bf16x4_t nv0 = *(const bf16x4_t*)(Vtb + (size_t)(qr     ) * SN + kn + 4 * g);
    bf16x4_t nv1 = *(const bf16x4_t*)(Vtb + (size_t)(qr + 16) * SN + kn + 4 * g);
    bf16x4_t nv2 = *(const bf16x4_t*)(Vtb + (size_t)(qr + 32) * SN + kn + 4 * g);
    bf16x4_t nv3 = *(const bf16x4_t*)(Vtb + (size_t)(qr + 48) * SN + kn + 4 * g);
    if ((t & 1) == 0) {
      wmA = bmb[(size_t)(kt >> 5) * SN + qA];
      wmB = bmb[(size_t)(kt >> 5) * SN + qB];
    }
    f32x4 aA = {0,0,0,0}, aB = {0,0,0,0};
    qk4_mfma(aA, aB, kf0, kf1, qfA0, qfA1, qfB0, qfB1);
    const int sh = (kt & 16) + 4 * g;
    float pA0 = (((wmA >> (sh + 0)) & 1u) ? 0.f : __expf(aA[0])) * rlA;
    float pA1 = (((wmA >> (sh + 1)) & 1u) ? 0.f : __expf(aA[1])) * rlA;
    float pA2 = (((wmA >> (sh + 2)) & 1u) ? 0.f : __expf(aA[2])) * rlA;
    float pA3 = (((wmA >> (sh + 3)) & 1u) ? 0.f : __expf(aA[3])) * rlA;
    float pB0 = (((wmB >> (sh + 0)) & 1u) ? 0.f : __expf(aB[0])) * rlB;
    float pB1 = (((wmB >> (sh + 1)) & 1u) ? 0.f : __expf(aB[1])) * rlB;
    float pB2 = (((wmB >> (sh + 2)) & 1u) ? 0.f : __expf(aB[2])) * rlB;
    float pB3 = (((wmB >> (sh + 3)) & 1u) ? 0.f : __expf(aB[3])) * rlB;
    *(f32x4*)(arowA + kt + 4 * g) = (f32x4){pA0, pA1, pA2, pA3};
    *(f32x4*)(arowB + kt + 4 * g) = (f32x4){pB0, pB1, pB2, pB3};
    bf16x4_t paA = {(__bf16)pA0, (__bf16)pA1, (__bf16)pA2, (__bf16)pA3};
    bf16x4_t paB = {(__bf16)pB0, (__bf16)pB1, (__bf16)pB2, (__bf16)pB3};
    pv8_mfma(cA0, cA1, cA2, cA3, cB0, cB1, cB2, cB3, paA, paB, vf0, vf1, vf2, vf3);
    kf0 = nk0; kf1 = nk1;
    vf0 = nv0; vf1 = nv1; vf2 = nv2; vf3 = nv3;
  }
  // ctx partial (f16): D-layout col dv = qr (+16*tile), row q = 4g+reg
  _Float16* cdst = cp + (size_t)c * CTXN;
  const size_t baseo = (size_t)bh * SN * DN;
  #pragma unroll
  for (int j = 0; j < 4; ++j) {
    const size_t rA = baseo + (size_t)(q0 + 4 * g + j) * DN + qr;
    const size_t rB = baseo + (size_t)(q0 + 16 + 4 * g + j) * DN + qr;
    cdst[rA]      = (_Float16)cA0[j];
    cdst[rA + 16] = (_Float16)cA1[j];
    cdst[rA + 32] = (_Float16)cA2[j];
    cdst[rA + 48] = (_Float16)cA3[j];
    cdst[rB]      = (_Float16)cB0[j];
    cdst[rB + 16] = (_Float16)cB1[j];
    cdst[rB + 32] = (_Float16)cB2[j];
    cdst[rB + 48] = (_Float16)cB3[j];
  }
}

// ---- sum the NK2 f16 partial contexts -> f32 ctx.
__global__ __launch_bounds__(256) void ctx_reduce_kernel(
    const _Float16* __restrict__ cp, float* __restrict__ ctx) {
  const size_t i = ((size_t)blockIdx.x * 256 + threadIdx.x) * 4;
  f16x4 a = *(const f16x4*)(cp + i);
  f16x4 b = *(const f16x4*)(cp + CTXN + i);
  f16x4 d = *(const f16x4*)(cp + 2 * CTXN + i);
  f16x4 e = *(const f16x4*)(cp + 3 * CTXN + i);
  f32x4 s;
  #pragma unroll
  for (int k = 0; k < 4; ++k)
    s[k] = ((float)a[k] + (float)b[k]) + ((float)d[k] + (float)e[k]);
  __builtin_nontemporal_store(s, (f32x4*)(ctx + i));
}

extern "C" void kernel_launch(void* const* d_in, const int* in_sizes, int n_in,
                              void* d_out, int out_size, void* d_ws, size_t ws_size,
                              hipStream_t stream) {
  const float* Q = (const float*)d_in[0];
  const float* K = (const float*)d_in[1];
  const float* V = (const float*)d_in[2];
  const unsigned int* mraw = (const unsigned int*)d_in[3];

  float* out  = (float*)d_out;
  float* ctx  = out;                 // CTXN f32
  float* attn = out + CTXN;          // 67,108,864 f32

  // ws layout (total ~38.3 MB; harness poison shows ws ~1 GB available)
  char* wsb = (char*)d_ws;
  unsigned int* flag = (unsigned int*)wsb;                       // 256 B
  unsigned int* bmT = (unsigned int*)(wsb + 256);                // 8 MB
  float* lp   = (float*)(wsb + 256 + 8388608);                   // 512 KB
  __bf16* Qb  = (__bf16*)(wsb + 256 + 8388608 + 524288);         // 4 MB
  __bf16* Kb  = (__bf16*)(wsb + 256 + 8388608 + 524288 + 4194304);
  __bf16* Vt  = (__bf16*)(wsb + 256 + 8388608 + 524288 + 2 * 4194304);
  _Float16* cp = (_Float16*)(wsb + 256 + 8388608 + 524288 + 3 * 4194304); // 16 MB

  detect_mask_kernel<<<1, 64, 0, stream>>>(mraw, flag);
  pack_mask_T_kernel<<<2048, 256, 0, stream>>>(mraw, bmT, flag);
  conv_qk_kernel<<<dim3(2048, 2), 256, 0, stream>>>(Q, K, Qb, Kb);
  conv_vt_kernel<<<dim3(16, BHN), 256, 0, stream>>>(V, Vt);

  attn_l_kernel<<<dim3(SN / 128, BHN, NK1), 256, 0, stream>>>(Qb, Kb, bmT, lp);
  attn_out_kernel<<<dim3(SN / 128, BHN, NK2), 256, 0, stream>>>(Qb, Kb, Vt, bmT,
                                                                lp, cp, attn);
  ctx_reduce_kernel<<<2048, 256, 0, stream>>>(cp, ctx);
}

// Round 7
// 232.805 us; speedup vs baseline: 2.0643x; 1.2820x over previous
//
#include <hip/hip_runtime.h>

typedef float f32x4 __attribute__((ext_vector_type(4)));
typedef _Float16 f16x4 __attribute__((ext_vector_type(4)));
typedef unsigned int u32x4 __attribute__((ext_vector_type(4)));
typedef __bf16 bf16x8_t __attribute__((ext_vector_type(8)));
typedef __bf16 bf16x4_t __attribute__((ext_vector_type(4)));

#define DEVFN static __device__ __forceinline__

constexpr int BHN = 16;    // B*H
constexpr int SN  = 2048;
constexpr int DN  = 64;
constexpr size_t CTXN = (size_t)BHN * SN * DN;   // 2,097,152
constexpr int NK1 = 4;    // k-split, pass 1
constexpr int NK2 = 4;    // k-split, pass 2

// ---- MFMA asm with internal hazard fencing (verified R2-R6).
DEVFN void qk4_mfma(f32x4& dA, f32x4& dB, bf16x8_t k0v, bf16x8_t k1v,
                    bf16x8_t qA0, bf16x8_t qA1, bf16x8_t qB0, bf16x8_t qB1) {
  asm volatile("s_nop 3\n\t"
               "v_mfma_f32_16x16x32_bf16 %0, %2, %4, %0\n\t"
               "v_mfma_f32_16x16x32_bf16 %1, %2, %6, %1\n\t"
               "v_mfma_f32_16x16x32_bf16 %0, %3, %5, %0\n\t"
               "v_mfma_f32_16x16x32_bf16 %1, %3, %7, %1\n\t"
               "s_nop 7\n\ts_nop 7"
               : "+v"(dA), "+v"(dB)
               : "v"(k0v), "v"(k1v), "v"(qA0), "v"(qA1), "v"(qB0), "v"(qB1));
}

DEVFN void pv8_mfma(f32x4& a0, f32x4& a1, f32x4& a2, f32x4& a3,
                    f32x4& b0, f32x4& b1, f32x4& b2, f32x4& b3,
                    bf16x4_t paA, bf16x4_t paB,
                    bf16x4_t v0, bf16x4_t v1, bf16x4_t v2, bf16x4_t v3) {
  asm volatile("s_nop 3\n\t"
               "v_mfma_f32_16x16x16_bf16 %0, %8, %10, %0\n\t"
               "v_mfma_f32_16x16x16_bf16 %4, %9, %10, %4\n\t"
               "v_mfma_f32_16x16x16_bf16 %1, %8, %11, %1\n\t"
               "v_mfma_f32_16x16x16_bf16 %5, %9, %11, %5\n\t"
               "v_mfma_f32_16x16x16_bf16 %2, %8, %12, %2\n\t"
               "v_mfma_f32_16x16x16_bf16 %6, %9, %12, %6\n\t"
               "v_mfma_f32_16x16x16_bf16 %3, %8, %13, %3\n\t"
               "v_mfma_f32_16x16x16_bf16 %7, %9, %13, %7\n\t"
               "s_nop 7\n\ts_nop 7"
               : "+v"(a0), "+v"(a1), "+v"(a2), "+v"(a3),
                 "+v"(b0), "+v"(b1), "+v"(b2), "+v"(b3)
               : "v"(paA), "v"(paB), "v"(v0), "v"(v1), "v"(v2), "v"(v3));
}

// ---- pack mask -> TRANSPOSED bitmask bmT[bh][k/32][q], with INLINE dtype
// detect (every block samples the first 16 KB; L2-hot after block 0).
__global__ __launch_bounds__(256) void pack_mask_T_kernel(
    const void* __restrict__ mraw, unsigned int* __restrict__ bmT) {
  __shared__ unsigned int sfl;
  if (threadIdx.x == 0) sfl = 0;
  __syncthreads();
  {
    unsigned int f = 0;
    const unsigned int* m32 = (const unsigned int*)mraw;
    for (int i = threadIdx.x; i < 4096; i += 256) {
      unsigned int w = m32[i];
      if (w == 0x3F800000u) f |= 2u;
      else if (w > 1u) f |= 1u;
    }
    if (f) atomicOr(&sfl, f);
  }
  __syncthreads();
  const unsigned int fl = (sfl & 2u) ? 2u : ((sfl & 1u) ? 1u : 0u);

  const int tid = blockIdx.x * 256 + threadIdx.x;
  const int NT  = gridDim.x * 256;
  if (fl != 1u) {
    // 4-byte elements (int32 or f32): one u32 word per (bh, kc2, q)
    const int W = BHN * (SN / 32) * SN;          // 2,097,152
    const unsigned int* m32 = (const unsigned int*)mraw;
    for (int w = tid; w < W; w += NT) {
      const int q   = w & (SN - 1);
      const int kc2 = (w >> 11) & (SN / 32 - 1);
      const int bh  = w >> 17;
      const unsigned int* src = m32 + ((size_t)(bh * SN + q) * SN) + kc2 * 32;
      unsigned int r = 0;
      #pragma unroll
      for (int j = 0; j < 8; ++j) {
        u32x4 v = *(const u32x4*)(src + j * 4);
        r |= ((unsigned)(v[0] != 0u)) << (4 * j)
           | ((unsigned)(v[1] != 0u)) << (4 * j + 1)
           | ((unsigned)(v[2] != 0u)) << (4 * j + 2)
           | ((unsigned)(v[3] != 0u)) << (4 * j + 3);
      }
      bmT[w] = r;
    }
  } else {
    // 1-byte elements
    const int W4 = BHN * (SN / 128) * SN;        // 524,288
    const unsigned char* m8 = (const unsigned char*)mraw;
    for (int w4 = tid; w4 < W4; w4 += NT) {
      const int q   = w4 & (SN - 1);
      const int kc8 = (w4 >> 11) & (SN / 128 - 1);
      const int bh  = w4 >> 15;
      const unsigned char* src = m8 + ((size_t)(bh * SN + q) * SN) + kc8 * 128;
      #pragma unroll
      for (int i = 0; i < 4; ++i) {
        const unsigned int* s32 = (const unsigned int*)(src + 32 * i);
        unsigned int r = 0;
        #pragma unroll
        for (int j = 0; j < 8; ++j) {
          unsigned int x = s32[j];
          r |= ((unsigned)((x & 0x000000FFu) != 0u)) << (4 * j)
             | ((unsigned)((x & 0x0000FF00u) != 0u)) << (4 * j + 1)
             | ((unsigned)((x & 0x00FF0000u) != 0u)) << (4 * j + 2)
             | ((unsigned)((x & 0xFF000000u) != 0u)) << (4 * j + 3);
        }
        bmT[((size_t)(bh * (SN / 32) + kc8 * 4 + i)) * SN + q] = r;
      }
    }
  }
}

// ---- f32 -> bf16 convert; y=0: Q (scale 1), y=1: K (scale 0.125, exact).
__global__ __launch_bounds__(256) void conv_qk_kernel(
    const float* __restrict__ Q, const float* __restrict__ K,
    __bf16* __restrict__ Qb, __bf16* __restrict__ Kb) {
  const size_t i = ((size_t)blockIdx.x * 256 + threadIdx.x) * 4;
  const float* src = blockIdx.y ? K : Q;
  __bf16* dst = blockIdx.y ? Kb : Qb;
  const float scale = blockIdx.y ? 0.125f : 1.0f;
  f32x4 v = *(const f32x4*)(src + i);
  bf16x4_t o = {(__bf16)(v[0] * scale), (__bf16)(v[1] * scale),
                (__bf16)(v[2] * scale), (__bf16)(v[3] * scale)};
  *(bf16x4_t*)(dst + i) = o;
}

// ---- V[k][d] f32 -> TILED Vt: [bh][k/32][d][k%32] bf16, 4 KB tiles.
__global__ __launch_bounds__(256) void conv_vt_kernel(
    const float* __restrict__ V, __bf16* __restrict__ Vt) {
  const int lane = threadIdx.x & 63, wv = threadIdx.x >> 6;
  const int k0 = (blockIdx.x * 4 + wv) * 32;
  const int bh = blockIdx.y;
  const float* src = V + (size_t)bh * SN * DN;
  // dst: tile (k0>>5), row d = lane, 32 bf16 contiguous
  __bf16* dst = Vt + (((size_t)bh * (SN / 32) + (k0 >> 5)) * DN + lane) * 32;
  bf16x8_t w0, w1, w2, w3;
  #pragma unroll
  for (int i = 0; i < 8; ++i) {
    w0[i] = (__bf16)src[(size_t)(k0 + i) * DN + lane];
    w1[i] = (__bf16)src[(size_t)(k0 + 8 + i) * DN + lane];
    w2[i] = (__bf16)src[(size_t)(k0 + 16 + i) * DN + lane];
    w3[i] = (__bf16)src[(size_t)(k0 + 24 + i) * DN + lane];
  }
  *(bf16x8_t*)(dst)      = w0;
  *(bf16x8_t*)(dst + 8)  = w1;
  *(bf16x8_t*)(dst + 16) = w2;
  *(bf16x8_t*)(dst + 24) = w3;
}

// XCD-pinning decode: all blocks of one bh land on one XCD (bid&7 == bh&7).
DEVFN void swz_decode(int bid, int& bh, int& c, int& x) {
  const int xcd = bid & 7, s8 = bid >> 3;   // s8: 0..127
  bh = xcd + 8 * (s8 >> 6);
  const int r6 = s8 & 63;
  c = r6 >> 4;
  x = r6 & 15;
}

// ---- pass 1: l-partials, 2 q-tiles/wave, direct K loads (R6 body + swizzle).
__global__ __launch_bounds__(256, 4) void attn_l_kernel(
    const __bf16* __restrict__ Qb, const __bf16* __restrict__ Kb,
    const unsigned int* __restrict__ bmT, float* __restrict__ lpart) {
  const int lane = threadIdx.x & 63, wv = threadIdx.x >> 6;
  const int qr = lane & 15, g = lane >> 4;
  int bh, c, x;
  swz_decode(blockIdx.x, bh, c, x);
  const int q0 = x * 128 + wv * 32;
  const int CS = SN / NK1, kbeg = c * CS;
  const __bf16* Qbb = Qb + (size_t)bh * SN * DN;
  const __bf16* Kbb = Kb + (size_t)bh * SN * DN;
  const int qA = q0 + qr, qB = q0 + 16 + qr;
  bf16x8_t qfA0 = *(const bf16x8_t*)(Qbb + (size_t)qA * DN + 8 * g);
  bf16x8_t qfA1 = *(const bf16x8_t*)(Qbb + (size_t)qA * DN + 32 + 8 * g);
  bf16x8_t qfB0 = *(const bf16x8_t*)(Qbb + (size_t)qB * DN + 8 * g);
  bf16x8_t qfB1 = *(const bf16x8_t*)(Qbb + (size_t)qB * DN + 32 + 8 * g);
  const size_t rowA = (size_t)bh * SN + qA;
  const size_t rowB = (size_t)bh * SN + qB;
  const unsigned int* bmb = bmT + (size_t)bh * (SN / 32) * SN;

  bf16x8_t kf0 = *(const bf16x8_t*)(Kbb + (size_t)(kbeg + qr) * DN + 8 * g);
  bf16x8_t kf1 = *(const bf16x8_t*)(Kbb + (size_t)(kbeg + qr) * DN + 32 + 8 * g);
  float lA = 0.f, lB = 0.f;
  unsigned int wmA = 0, wmB = 0;
  #pragma unroll 2
  for (int t = 0; t < CS / 16; ++t) {
    const int kt = kbeg + t * 16;
    const int kn = kbeg + ((t + 1) & (CS / 16 - 1)) * 16;   // clamped wrap
    bf16x8_t nk0 = *(const bf16x8_t*)(Kbb + (size_t)(kn + qr) * DN + 8 * g);
    bf16x8_t nk1 = *(const bf16x8_t*)(Kbb + (size_t)(kn + qr) * DN + 32 + 8 * g);
    if ((t & 1) == 0) {
      wmA = bmb[(size_t)(kt >> 5) * SN + qA];
      wmB = bmb[(size_t)(kt >> 5) * SN + qB];
    }
    f32x4 aA = {0,0,0,0}, aB = {0,0,0,0};
    qk4_mfma(aA, aB, kf0, kf1, qfA0, qfA1, qfB0, qfB1);
    const int sh = (kt & 16) + 4 * g;
    lA += ((wmA >> (sh + 0)) & 1u) ? 0.f : __expf(aA[0]);
    lA += ((wmA >> (sh + 1)) & 1u) ? 0.f : __expf(aA[1]);
    lA += ((wmA >> (sh + 2)) & 1u) ? 0.f : __expf(aA[2]);
    lA += ((wmA >> (sh + 3)) & 1u) ? 0.f : __expf(aA[3]);
    lB += ((wmB >> (sh + 0)) & 1u) ? 0.f : __expf(aB[0]);
    lB += ((wmB >> (sh + 1)) & 1u) ? 0.f : __expf(aB[1]);
    lB += ((wmB >> (sh + 2)) & 1u) ? 0.f : __expf(aB[2]);
    lB += ((wmB >> (sh + 3)) & 1u) ? 0.f : __expf(aB[3]);
    kf0 = nk0; kf1 = nk1;
  }
  lA = lA + __shfl_xor(lA, 16); lA = lA + __shfl_xor(lA, 32);
  lB = lB + __shfl_xor(lB, 16); lB = lB + __shfl_xor(lB, 32);
  if (g == 0) {
    lpart[rowA * NK1 + c] = lA;
    lpart[rowB * NK1 + c] = lB;
  }
}

// ---- pass 2: LDS-staged K+V (double-buffered, XOR-swizzled), 2 q-tiles/wave.
// Per 32-k tile: stage K 4 KB + V 4 KB coalesced (16 B/thread), one barrier.
__global__ __launch_bounds__(256, 4) void attn_out_kernel(
    const __bf16* __restrict__ Qb, const __bf16* __restrict__ Kb,
    const __bf16* __restrict__ Vt, const unsigned int* __restrict__ bmT,
    const float* __restrict__ lpart, _Float16* __restrict__ cp,
    float* __restrict__ attn) {
  __shared__ __align__(16) char Ks[2][4096];
  __shared__ __align__(16) char Vs[2][4096];
  const int tid = threadIdx.x;
  const int lane = tid & 63, wv = tid >> 6;
  const int qr = lane & 15, g = lane >> 4;
  int bh, c, x;
  swz_decode(blockIdx.x, bh, c, x);
  const int q0 = x * 128 + wv * 32;
  const int CS = SN / NK2, kbase = c * CS;  // 512
  const int NT = CS / 32;                   // 16 tiles

  const __bf16* Qbb = Qb + (size_t)bh * SN * DN;
  const int qA = q0 + qr, qB = q0 + 16 + qr;
  bf16x8_t qfA0 = *(const bf16x8_t*)(Qbb + (size_t)qA * DN + 8 * g);
  bf16x8_t qfA1 = *(const bf16x8_t*)(Qbb + (size_t)qA * DN + 32 + 8 * g);
  bf16x8_t qfB0 = *(const bf16x8_t*)(Qbb + (size_t)qB * DN + 8 * g);
  bf16x8_t qfB1 = *(const bf16x8_t*)(Qbb + (size_t)qB * DN + 32 + 8 * g);
  const size_t rowA = (size_t)bh * SN + qA;
  const size_t rowB = (size_t)bh * SN + qB;
  f32x4 l4A = *(const f32x4*)(lpart + rowA * NK1);
  f32x4 l4B = *(const f32x4*)(lpart + rowB * NK1);
  const float rlA = 1.0f / (l4A[0] + l4A[1] + l4A[2] + l4A[3]);
  const float rlB = 1.0f / (l4B[0] + l4B[1] + l4B[2] + l4B[3]);
  const unsigned int* bmb = bmT + (size_t)bh * (SN / 32) * SN;
  float* arowA = attn + rowA * SN;
  float* arowB = attn + rowB * SN;

  // staging addressing (16 B per thread for K and for V)
  const int krow = tid >> 3;                 // 0..31
  const int kcolb = (tid & 7) * 16;          // 0..112
  const int kdst = krow * 128 + (kcolb ^ ((krow & 7) << 4));
  const char* Ksrc = (const char*)(Kb + (size_t)bh * SN * DN + (size_t)kbase * DN);
  const int vd = tid >> 2;                   // 0..63
  const int vkb = (tid & 3) * 16;            // 0..48
  const int vdst0 = vd * 64 + ((vkb    ) ^ ((vd & 7) << 3));
  const int vdst1 = vd * 64 + ((vkb + 8) ^ ((vd & 7) << 3));
  const char* Vsrc = (const char*)Vt + ((size_t)bh * (SN / 32) + (kbase >> 5)) * 4096;

  f32x4 cA0 = {0,0,0,0}, cA1 = {0,0,0,0}, cA2 = {0,0,0,0}, cA3 = {0,0,0,0};
  f32x4 cB0 = {0,0,0,0}, cB1 = {0,0,0,0}, cB2 = {0,0,0,0}, cB3 = {0,0,0,0};

  // prologue: stage tile 0 into buffer 0
  {
    u32x4 kr = *(const u32x4*)(Ksrc + krow * 128 + kcolb);
    u32x4 vr = *(const u32x4*)(Vsrc + tid * 16);
    *(u32x4*)&Ks[0][kdst] = kr;
    *(unsigned long long*)&Vs[0][vdst0] =
        ((unsigned long long)vr[1] << 32) | vr[0];
    *(unsigned long long*)&Vs[0][vdst1] =
        ((unsigned long long)vr[3] << 32) | vr[2];
  }
  __syncthreads();

  for (int tt = 0; tt < NT; ++tt) {
    const bool pf = (tt + 1 < NT);
    u32x4 kr, vr;
    if (pf) {   // T14: issue next-tile loads before compute
      kr = *(const u32x4*)(Ksrc + (tt + 1) * 4096 + krow * 128 + kcolb);
      vr = *(const u32x4*)(Vsrc + (tt + 1) * 4096 + tid * 16);
    }
    const char* Kbuf = Ks[tt & 1];
    const char* Vbuf = Vs[tt & 1];
    const int ktg = kbase + tt * 32;
    const unsigned int wmA = bmb[(size_t)((kbase >> 5) + tt) * SN + qA];
    const unsigned int wmB = bmb[(size_t)((kbase >> 5) + tt) * SN + qB];
    #pragma unroll
    for (int s = 0; s < 2; ++s) {
      const int rk = 16 * s + qr;
      bf16x8_t kf0 = *(const bf16x8_t*)&Kbuf[rk * 128 + ((16 * g     ) ^ ((rk & 7) << 4))];
      bf16x8_t kf1 = *(const bf16x8_t*)&Kbuf[rk * 128 + ((64 + 16 * g) ^ ((rk & 7) << 4))];
      const int vxor = (32 * s + 8 * g) ^ ((qr & 7) << 3);
      bf16x4_t vf0 = *(const bf16x4_t*)&Vbuf[(qr     ) * 64 + vxor];
      bf16x4_t vf1 = *(const bf16x4_t*)&Vbuf[(qr + 16) * 64 + vxor];
      bf16x4_t vf2 = *(const bf16x4_t*)&Vbuf[(qr + 32) * 64 + vxor];
      bf16x4_t vf3 = *(const bf16x4_t*)&Vbuf[(qr + 48) * 64 + vxor];
      f32x4 aA = {0,0,0,0}, aB = {0,0,0,0};
      qk4_mfma(aA, aB, kf0, kf1, qfA0, qfA1, qfB0, qfB1);
      const int sh = 16 * s + 4 * g;
      float pA0 = (((wmA >> (sh + 0)) & 1u) ? 0.f : __expf(aA[0])) * rlA;
      float pA1 = (((wmA >> (sh + 1)) & 1u) ? 0.f : __expf(aA[1])) * rlA;
      float pA2 = (((wmA >> (sh + 2)) & 1u) ? 0.f : __expf(aA[2])) * rlA;
      float pA3 = (((wmA >> (sh + 3)) & 1u) ? 0.f : __expf(aA[3])) * rlA;
      float pB0 = (((wmB >> (sh + 0)) & 1u) ? 0.f : __expf(aB[0])) * rlB;
      float pB1 = (((wmB >> (sh + 1)) & 1u) ? 0.f : __expf(aB[1])) * rlB;
      float pB2 = (((wmB >> (sh + 2)) & 1u) ? 0.f : __expf(aB[2])) * rlB;
      float pB3 = (((wmB >> (sh + 3)) & 1u) ? 0.f : __expf(aB[3])) * rlB;
      *(f32x4*)(arowA + ktg + sh) = (f32x4){pA0, pA1, pA2, pA3};
      *(f32x4*)(arowB + ktg + sh) = (f32x4){pB0, pB1, pB2, pB3};
      bf16x4_t paA = {(__bf16)pA0, (__bf16)pA1, (__bf16)pA2, (__bf16)pA3};
      bf16x4_t paB = {(__bf16)pB0, (__bf16)pB1, (__bf16)pB2, (__bf16)pB3};
      pv8_mfma(cA0, cA1, cA2, cA3, cB0, cB1, cB2, cB3, paA, paB, vf0, vf1, vf2, vf3);
    }
    if (pf) {   // write-late: LDS writes wait on the loads via vmcnt
      char* Kn = Ks[(tt + 1) & 1];
      char* Vn = Vs[(tt + 1) & 1];
      *(u32x4*)&Kn[kdst] = kr;
      *(unsigned long long*)&Vn[vdst0] = ((unsigned long long)vr[1] << 32) | vr[0];
      *(unsigned long long*)&Vn[vdst1] = ((unsigned long long)vr[3] << 32) | vr[2];
    }
    __syncthreads();
  }
  // ctx partial (f16): D-layout col dv = qr (+16*tile), row q = 4g+reg
  _Float16* cdst = cp + (size_t)c * CTXN;
  const size_t baseo = (size_t)bh * SN * DN;
  #pragma unroll
  for (int j = 0; j < 4; ++j) {
    const size_t rA = baseo + (size_t)(q0 + 4 * g + j) * DN + qr;
    const size_t rB = baseo + (size_t)(q0 + 16 + 4 * g + j) * DN + qr;
    cdst[rA]      = (_Float16)cA0[j];
    cdst[rA + 16] = (_Float16)cA1[j];
    cdst[rA + 32] = (_Float16)cA2[j];
    cdst[rA + 48] = (_Float16)cA3[j];
    cdst[rB]      = (_Float16)cB0[j];
    cdst[rB + 16] = (_Float16)cB1[j];
    cdst[rB + 32] = (_Float16)cB2[j];
    cdst[rB + 48] = (_Float16)cB3[j];
  }
}

// ---- sum the NK2 f16 partial contexts -> f32 ctx.
__global__ __launch_bounds__(256) void ctx_reduce_kernel(
    const _Float16* __restrict__ cp, float* __restrict__ ctx) {
  const size_t i = ((size_t)blockIdx.x * 256 + threadIdx.x) * 4;
  f16x4 a = *(const f16x4*)(cp + i);
  f16x4 b = *(const f16x4*)(cp + CTXN + i);
  f16x4 d = *(const f16x4*)(cp + 2 * CTXN + i);
  f16x4 e = *(const f16x4*)(cp + 3 * CTXN + i);
  f32x4 s;
  #pragma unroll
  for (int k = 0; k < 4; ++k)
    s[k] = ((float)a[k] + (float)b[k]) + ((float)d[k] + (float)e[k]);
  __builtin_nontemporal_store(s, (f32x4*)(ctx + i));
}

extern "C" void kernel_launch(void* const* d_in, const int* in_sizes, int n_in,
                              void* d_out, int out_size, void* d_ws, size_t ws_size,
                              hipStream_t stream) {
  const float* Q = (const float*)d_in[0];
  const float* K = (const float*)d_in[1];
  const float* V = (const float*)d_in[2];
  const void*  mraw = d_in[3];

  float* out  = (float*)d_out;
  float* ctx  = out;                 // CTXN f32
  float* attn = out + CTXN;          // 67,108,864 f32

  // ws layout (~38.3 MB)
  char* wsb = (char*)d_ws;
  unsigned int* bmT = (unsigned int*)(wsb + 256);                // 8 MB
  float* lp   = (float*)(wsb + 256 + 8388608);                   // 512 KB
  __bf16* Qb  = (__bf16*)(wsb + 256 + 8388608 + 524288);         // 4 MB
  __bf16* Kb  = (__bf16*)(wsb + 256 + 8388608 + 524288 + 4194304);
  __bf16* Vt  = (__bf16*)(wsb + 256 + 8388608 + 524288 + 2 * 4194304);
  _Float16* cp = (_Float16*)(wsb + 256 + 8388608 + 524288 + 3 * 4194304); // 16 MB

  pack_mask_T_kernel<<<2048, 256, 0, stream>>>(mraw, bmT);
  conv_qk_kernel<<<dim3(2048, 2), 256, 0, stream>>>(Q, K, Qb, Kb);
  conv_vt_kernel<<<dim3(16, BHN), 256, 0, stream>>>(V, Vt);

  attn_l_kernel<<<1024, 256, 0, stream>>>(Qb, Kb, bmT, lp);
  attn_out_kernel<<<1024, 256, 0, stream>>>(Qb, Kb, Vt, bmT, lp, cp, attn);
  ctx_reduce_kernel<<<2048, 256, 0, stream>>>(cp, ctx);
}

// Round 8
// 201.591 us; speedup vs baseline: 2.3840x; 1.1548x over previous
//
#include <hip/hip_runtime.h>

typedef float f32x4 __attribute__((ext_vector_type(4)));
typedef _Float16 f16x4 __attribute__((ext_vector_type(4)));
typedef unsigned int u32x4 __attribute__((ext_vector_type(4)));
typedef __bf16 bf16x8_t __attribute__((ext_vector_type(8)));
typedef __bf16 bf16x4_t __attribute__((ext_vector_type(4)));

#define DEVFN static __device__ __forceinline__

constexpr int BHN = 16;    // B*H
constexpr int SN  = 2048;
constexpr int DN  = 64;
constexpr size_t CTXN = (size_t)BHN * SN * DN;   // 2,097,152
constexpr int NK1 = 4;    // k-split, pass 1
constexpr int NK2 = 4;    // k-split, pass 2

// ---- MFMA asm with internal hazard fencing (verified R2-R7).
DEVFN void qk4_mfma(f32x4& dA, f32x4& dB, bf16x8_t k0v, bf16x8_t k1v,
                    bf16x8_t qA0, bf16x8_t qA1, bf16x8_t qB0, bf16x8_t qB1) {
  asm volatile("s_nop 3\n\t"
               "v_mfma_f32_16x16x32_bf16 %0, %2, %4, %0\n\t"
               "v_mfma_f32_16x16x32_bf16 %1, %2, %6, %1\n\t"
               "v_mfma_f32_16x16x32_bf16 %0, %3, %5, %0\n\t"
               "v_mfma_f32_16x16x32_bf16 %1, %3, %7, %1\n\t"
               "s_nop 7\n\ts_nop 7"
               : "+v"(dA), "+v"(dB)
               : "v"(k0v), "v"(k1v), "v"(qA0), "v"(qA1), "v"(qB0), "v"(qB1));
}

DEVFN void pv8_mfma(f32x4& a0, f32x4& a1, f32x4& a2, f32x4& a3,
                    f32x4& b0, f32x4& b1, f32x4& b2, f32x4& b3,
                    bf16x4_t paA, bf16x4_t paB,
                    bf16x4_t v0, bf16x4_t v1, bf16x4_t v2, bf16x4_t v3) {
  asm volatile("s_nop 3\n\t"
               "v_mfma_f32_16x16x16_bf16 %0, %8, %10, %0\n\t"
               "v_mfma_f32_16x16x16_bf16 %4, %9, %10, %4\n\t"
               "v_mfma_f32_16x16x16_bf16 %1, %8, %11, %1\n\t"
               "v_mfma_f32_16x16x16_bf16 %5, %9, %11, %5\n\t"
               "v_mfma_f32_16x16x16_bf16 %2, %8, %12, %2\n\t"
               "v_mfma_f32_16x16x16_bf16 %6, %9, %12, %6\n\t"
               "v_mfma_f32_16x16x16_bf16 %3, %8, %13, %3\n\t"
               "v_mfma_f32_16x16x16_bf16 %7, %9, %13, %7\n\t"
               "s_nop 7\n\ts_nop 7"
               : "+v"(a0), "+v"(a1), "+v"(a2), "+v"(a3),
                 "+v"(b0), "+v"(b1), "+v"(b2), "+v"(b3)
               : "v"(paA), "v"(paB), "v"(v0), "v"(v1), "v"(v2), "v"(v3));
}

// ---- FUSED prep: blocks [0,2048) pack mask->bmT; [2048,3072) Q->bf16;
// [3072,4096) K->bf16*0.125; [4096,4352) V->tiled Vt.
constexpr int PB = 2048, QB = 1024, KB = 1024, VB = 256;

__global__ __launch_bounds__(256) void prep_kernel(
    const void* __restrict__ mraw, unsigned int* __restrict__ bmT,
    const float* __restrict__ Q, const float* __restrict__ K,
    const float* __restrict__ V, __bf16* __restrict__ Qb,
    __bf16* __restrict__ Kb, __bf16* __restrict__ Vt) {
  const int bid = blockIdx.x;
  const int tidl = threadIdx.x;
  if (bid < PB) {
    // ---- pack mask -> TRANSPOSED bitmask bmT[bh][k/32][q], inline detect.
    __shared__ unsigned int sfl;
    if (tidl == 0) sfl = 0;
    __syncthreads();
    {
      unsigned int f = 0;
      const unsigned int* m32 = (const unsigned int*)mraw;
      for (int i = tidl; i < 4096; i += 256) {
        unsigned int w = m32[i];
        if (w == 0x3F800000u) f |= 2u;
        else if (w > 1u) f |= 1u;
      }
      if (f) atomicOr(&sfl, f);
    }
    __syncthreads();
    const unsigned int fl = (sfl & 2u) ? 2u : ((sfl & 1u) ? 1u : 0u);
    const int tid = bid * 256 + tidl;
    const int NT  = PB * 256;
    if (fl != 1u) {
      const int W = BHN * (SN / 32) * SN;          // 2,097,152
      const unsigned int* m32 = (const unsigned int*)mraw;
      for (int w = tid; w < W; w += NT) {
        const int q   = w & (SN - 1);
        const int kc2 = (w >> 11) & (SN / 32 - 1);
        const int bh  = w >> 17;
        const unsigned int* src = m32 + ((size_t)(bh * SN + q) * SN) + kc2 * 32;
        unsigned int r = 0;
        #pragma unroll
        for (int j = 0; j < 8; ++j) {
          u32x4 v = *(const u32x4*)(src + j * 4);
          r |= ((unsigned)(v[0] != 0u)) << (4 * j)
             | ((unsigned)(v[1] != 0u)) << (4 * j + 1)
             | ((unsigned)(v[2] != 0u)) << (4 * j + 2)
             | ((unsigned)(v[3] != 0u)) << (4 * j + 3);
        }
        bmT[w] = r;
      }
    } else {
      const int W4 = BHN * (SN / 128) * SN;        // 524,288
      const unsigned char* m8 = (const unsigned char*)mraw;
      for (int w4 = tid; w4 < W4; w4 += NT) {
        const int q   = w4 & (SN - 1);
        const int kc8 = (w4 >> 11) & (SN / 128 - 1);
        const int bh  = w4 >> 15;
        const unsigned char* src = m8 + ((size_t)(bh * SN + q) * SN) + kc8 * 128;
        #pragma unroll
        for (int i = 0; i < 4; ++i) {
          const unsigned int* s32 = (const unsigned int*)(src + 32 * i);
          unsigned int r = 0;
          #pragma unroll
          for (int j = 0; j < 8; ++j) {
            unsigned int x = s32[j];
            r |= ((unsigned)((x & 0x000000FFu) != 0u)) << (4 * j)
               | ((unsigned)((x & 0x0000FF00u) != 0u)) << (4 * j + 1)
               | ((unsigned)((x & 0x00FF0000u) != 0u)) << (4 * j + 2)
               | ((unsigned)((x & 0xFF000000u) != 0u)) << (4 * j + 3);
          }
          bmT[((size_t)(bh * (SN / 32) + kc8 * 4 + i)) * SN + q] = r;
        }
      }
    }
  } else if (bid < PB + QB + KB) {
    // ---- f32 -> bf16 convert (Q scale 1, K scale 0.125 exact).
    const bool isK = (bid >= PB + QB);
    const int rb = bid - (isK ? PB + QB : PB);
    const float* src = isK ? K : Q;
    __bf16* dst = isK ? Kb : Qb;
    const float scale = isK ? 0.125f : 1.0f;
    const size_t i = ((size_t)rb * 256 + tidl) * 8;
    f32x4 v0 = *(const f32x4*)(src + i);
    f32x4 v1 = *(const f32x4*)(src + i + 4);
    bf16x8_t o;
    o[0]=(__bf16)(v0[0]*scale); o[1]=(__bf16)(v0[1]*scale);
    o[2]=(__bf16)(v0[2]*scale); o[3]=(__bf16)(v0[3]*scale);
    o[4]=(__bf16)(v1[0]*scale); o[5]=(__bf16)(v1[1]*scale);
    o[6]=(__bf16)(v1[2]*scale); o[7]=(__bf16)(v1[3]*scale);
    *(bf16x8_t*)(dst + i) = o;
  } else {
    // ---- V[k][d] f32 -> TILED Vt: [bh][k/32][d][k%32] bf16 (4 KB tiles).
    const int vb = bid - (PB + QB + KB);
    const int lane = tidl & 63, wv = tidl >> 6;
    const int k0 = ((vb & 15) * 4 + wv) * 32;
    const int bh = vb >> 4;
    const float* src = V + (size_t)bh * SN * DN;
    __bf16* dst = Vt + (((size_t)bh * (SN / 32) + (k0 >> 5)) * DN + lane) * 32;
    bf16x8_t w0, w1, w2, w3;
    #pragma unroll
    for (int i = 0; i < 8; ++i) {
      w0[i] = (__bf16)src[(size_t)(k0 + i) * DN + lane];
      w1[i] = (__bf16)src[(size_t)(k0 + 8 + i) * DN + lane];
      w2[i] = (__bf16)src[(size_t)(k0 + 16 + i) * DN + lane];
      w3[i] = (__bf16)src[(size_t)(k0 + 24 + i) * DN + lane];
    }
    *(bf16x8_t*)(dst)      = w0;
    *(bf16x8_t*)(dst + 8)  = w1;
    *(bf16x8_t*)(dst + 16) = w2;
    *(bf16x8_t*)(dst + 24) = w3;
  }
}

// XCD-pinning decode: all blocks of one bh land on one XCD (bid&7 == bh&7).
DEVFN void swz_decode(int bid, int& bh, int& c, int& x) {
  const int xcd = bid & 7, s8 = bid >> 3;   // s8: 0..127
  bh = xcd + 8 * (s8 >> 6);
  const int r6 = s8 & 63;
  c = r6 >> 4;
  x = r6 & 15;
}

// ---- pass 1: l-partials. LDS-staged K (64-k tiles, double-buffered,
// XOR-swizzled), 2 q-tiles/wave, T14 issue-early/write-late.
__global__ __launch_bounds__(256, 4) void attn_l_kernel(
    const __bf16* __restrict__ Qb, const __bf16* __restrict__ Kb,
    const unsigned int* __restrict__ bmT, float* __restrict__ lpart) {
  __shared__ __align__(16) char Ks[2][8192];
  const int tid = threadIdx.x;
  const int lane = tid & 63, wv = tid >> 6;
  const int qr = lane & 15, g = lane >> 4;
  int bh, c, x;
  swz_decode(blockIdx.x, bh, c, x);
  const int q0 = x * 128 + wv * 32;
  const int CS = SN / NK1, kbase = c * CS;   // 512
  const int NT = CS / 64;                    // 8 tiles

  const __bf16* Qbb = Qb + (size_t)bh * SN * DN;
  const int qA = q0 + qr, qB = q0 + 16 + qr;
  bf16x8_t qfA0 = *(const bf16x8_t*)(Qbb + (size_t)qA * DN + 8 * g);
  bf16x8_t qfA1 = *(const bf16x8_t*)(Qbb + (size_t)qA * DN + 32 + 8 * g);
  bf16x8_t qfB0 = *(const bf16x8_t*)(Qbb + (size_t)qB * DN + 8 * g);
  bf16x8_t qfB1 = *(const bf16x8_t*)(Qbb + (size_t)qB * DN + 32 + 8 * g);
  const size_t rowA = (size_t)bh * SN + qA;
  const size_t rowB = (size_t)bh * SN + qB;
  const unsigned int* bmb = bmT + (size_t)bh * (SN / 32) * SN;
  const int kb2 = kbase >> 5;

  // staging: 8 KB / 256 thr = 32 B/thread (2 x u32x4)
  const int krow = tid >> 2;                 // 0..63
  const int kcol = (tid & 3) * 32;           // 0,32,64,96
  const int swz  = (krow & 7) << 4;
  const int kdst0 = krow * 128 + ((kcol     ) ^ swz);
  const int kdst1 = krow * 128 + ((kcol + 16) ^ swz);
  const char* Ksrc = (const char*)(Kb + (size_t)bh * SN * DN + (size_t)kbase * DN);

  {
    u32x4 a = *(const u32x4*)(Ksrc + krow * 128 + kcol);
    u32x4 b = *(const u32x4*)(Ksrc + krow * 128 + kcol + 16);
    *(u32x4*)&Ks[0][kdst0] = a;
    *(u32x4*)&Ks[0][kdst1] = b;
  }
  __syncthreads();

  float lA = 0.f, lB = 0.f;
  for (int tt = 0; tt < NT; ++tt) {
    const bool pf = (tt + 1 < NT);
    u32x4 a, b;
    if (pf) {
      a = *(const u32x4*)(Ksrc + (tt + 1) * 8192 + krow * 128 + kcol);
      b = *(const u32x4*)(Ksrc + (tt + 1) * 8192 + krow * 128 + kcol + 16);
    }
    const char* Kbuf = Ks[tt & 1];
    const unsigned int wA0 = bmb[(size_t)(kb2 + 2 * tt    ) * SN + qA];
    const unsigned int wA1 = bmb[(size_t)(kb2 + 2 * tt + 1) * SN + qA];
    const unsigned int wB0 = bmb[(size_t)(kb2 + 2 * tt    ) * SN + qB];
    const unsigned int wB1 = bmb[(size_t)(kb2 + 2 * tt + 1) * SN + qB];
    #pragma unroll
    for (int s = 0; s < 4; ++s) {
      const int rk = 16 * s + qr;
      const int rsw = (rk & 7) << 4;
      bf16x8_t kf0 = *(const bf16x8_t*)&Kbuf[rk * 128 + ((16 * g     ) ^ rsw)];
      bf16x8_t kf1 = *(const bf16x8_t*)&Kbuf[rk * 128 + ((64 + 16 * g) ^ rsw)];
      f32x4 aA = {0,0,0,0}, aB = {0,0,0,0};
      qk4_mfma(aA, aB, kf0, kf1, qfA0, qfA1, qfB0, qfB1);
      const unsigned int wmA = (s < 2) ? wA0 : wA1;
      const unsigned int wmB = (s < 2) ? wB0 : wB1;
      const int sh = (s & 1) * 16 + 4 * g;
      lA += ((wmA >> (sh + 0)) & 1u) ? 0.f : __expf(aA[0]);
      lA += ((wmA >> (sh + 1)) & 1u) ? 0.f : __expf(aA[1]);
      lA += ((wmA >> (sh + 2)) & 1u) ? 0.f : __expf(aA[2]);
      lA += ((wmA >> (sh + 3)) & 1u) ? 0.f : __expf(aA[3]);
      lB += ((wmB >> (sh + 0)) & 1u) ? 0.f : __expf(aB[0]);
      lB += ((wmB >> (sh + 1)) & 1u) ? 0.f : __expf(aB[1]);
      lB += ((wmB >> (sh + 2)) & 1u) ? 0.f : __expf(aB[2]);
      lB += ((wmB >> (sh + 3)) & 1u) ? 0.f : __expf(aB[3]);
    }
    if (pf) {
      char* Kn = Ks[(tt + 1) & 1];
      *(u32x4*)&Kn[kdst0] = a;
      *(u32x4*)&Kn[kdst1] = b;
    }
    __syncthreads();
  }
  lA = lA + __shfl_xor(lA, 16); lA = lA + __shfl_xor(lA, 32);
  lB = lB + __shfl_xor(lB, 16); lB = lB + __shfl_xor(lB, 32);
  if (g == 0) {
    lpart[rowA * NK1 + c] = lA;
    lpart[rowB * NK1 + c] = lB;
  }
}

// ---- pass 2: UNCHANGED from R7 (proven): LDS-staged K+V, 2 q-tiles/wave.
__global__ __launch_bounds__(256, 4) void attn_out_kernel(
    const __bf16* __restrict__ Qb, const __bf16* __restrict__ Kb,
    const __bf16* __restrict__ Vt, const unsigned int* __restrict__ bmT,
    const float* __restrict__ lpart, _Float16* __restrict__ cp,
    float* __restrict__ attn) {
  __shared__ __align__(16) char Ks[2][4096];
  __shared__ __align__(16) char Vs[2][4096];
  const int tid = threadIdx.x;
  const int lane = tid & 63, wv = tid >> 6;
  const int qr = lane & 15, g = lane >> 4;
  int bh, c, x;
  swz_decode(blockIdx.x, bh, c, x);
  const int q0 = x * 128 + wv * 32;
  const int CS = SN / NK2, kbase = c * CS;  // 512
  const int NT = CS / 32;                   // 16 tiles

  const __bf16* Qbb = Qb + (size_t)bh * SN * DN;
  const int qA = q0 + qr, qB = q0 + 16 + qr;
  bf16x8_t qfA0 = *(const bf16x8_t*)(Qbb + (size_t)qA * DN + 8 * g);
  bf16x8_t qfA1 = *(const bf16x8_t*)(Qbb + (size_t)qA * DN + 32 + 8 * g);
  bf16x8_t qfB0 = *(const bf16x8_t*)(Qbb + (size_t)qB * DN + 8 * g);
  bf16x8_t qfB1 = *(const bf16x8_t*)(Qbb + (size_t)qB * DN + 32 + 8 * g);
  const size_t rowA = (size_t)bh * SN + qA;
  const size_t rowB = (size_t)bh * SN + qB;
  f32x4 l4A = *(const f32x4*)(lpart + rowA * NK1);
  f32x4 l4B = *(const f32x4*)(lpart + rowB * NK1);
  const float rlA = 1.0f / (l4A[0] + l4A[1] + l4A[2] + l4A[3]);
  const float rlB = 1.0f / (l4B[0] + l4B[1] + l4B[2] + l4B[3]);
  const unsigned int* bmb = bmT + (size_t)bh * (SN / 32) * SN;
  float* arowA = attn + rowA * SN;
  float* arowB = attn + rowB * SN;

  const int krow = tid >> 3;                 // 0..31
  const int kcolb = (tid & 7) * 16;          // 0..112
  const int kdst = krow * 128 + (kcolb ^ ((krow & 7) << 4));
  const char* Ksrc = (const char*)(Kb + (size_t)bh * SN * DN + (size_t)kbase * DN);
  const int vd = tid >> 2;                   // 0..63
  const int vkb = (tid & 3) * 16;            // 0..48
  const int vdst0 = vd * 64 + ((vkb    ) ^ ((vd & 7) << 3));
  const int vdst1 = vd * 64 + ((vkb + 8) ^ ((vd & 7) << 3));
  const char* Vsrc = (const char*)Vt + ((size_t)bh * (SN / 32) + (kbase >> 5)) * 4096;

  f32x4 cA0 = {0,0,0,0}, cA1 = {0,0,0,0}, cA2 = {0,0,0,0}, cA3 = {0,0,0,0};
  f32x4 cB0 = {0,0,0,0}, cB1 = {0,0,0,0}, cB2 = {0,0,0,0}, cB3 = {0,0,0,0};

  {
    u32x4 kr = *(const u32x4*)(Ksrc + krow * 128 + kcolb);
    u32x4 vr = *(const u32x4*)(Vsrc + tid * 16);
    *(u32x4*)&Ks[0][kdst] = kr;
    *(unsigned long long*)&Vs[0][vdst0] =
        ((unsigned long long)vr[1] << 32) | vr[0];
    *(unsigned long long*)&Vs[0][vdst1] =
        ((unsigned long long)vr[3] << 32) | vr[2];
  }
  __syncthreads();

  for (int tt = 0; tt < NT; ++tt) {
    const bool pf = (tt + 1 < NT);
    u32x4 kr, vr;
    if (pf) {
      kr = *(const u32x4*)(Ksrc + (tt + 1) * 4096 + krow * 128 + kcolb);
      vr = *(const u32x4*)(Vsrc + (tt + 1) * 4096 + tid * 16);
    }
    const char* Kbuf = Ks[tt & 1];
    const char* Vbuf = Vs[tt & 1];
    const int ktg = kbase + tt * 32;
    const unsigned int wmA = bmb[(size_t)((kbase >> 5) + tt) * SN + qA];
    const unsigned int wmB = bmb[(size_t)((kbase >> 5) + tt) * SN + qB];
    #pragma unroll
    for (int s = 0; s < 2; ++s) {
      const int rk = 16 * s + qr;
      bf16x8_t kf0 = *(const bf16x8_t*)&Kbuf[rk * 128 + ((16 * g     ) ^ ((rk & 7) << 4))];
      bf16x8_t kf1 = *(const bf16x8_t*)&Kbuf[rk * 128 + ((64 + 16 * g) ^ ((rk & 7) << 4))];
      const int vxor = (32 * s + 8 * g) ^ ((qr & 7) << 3);
      bf16x4_t vf0 = *(const bf16x4_t*)&Vbuf[(qr     ) * 64 + vxor];
      bf16x4_t vf1 = *(const bf16x4_t*)&Vbuf[(qr + 16) * 64 + vxor];
      bf16x4_t vf2 = *(const bf16x4_t*)&Vbuf[(qr + 32) * 64 + vxor];
      bf16x4_t vf3 = *(const bf16x4_t*)&Vbuf[(qr + 48) * 64 + vxor];
      f32x4 aA = {0,0,0,0}, aB = {0,0,0,0};
      qk4_mfma(aA, aB, kf0, kf1, qfA0, qfA1, qfB0, qfB1);
      const int sh = 16 * s + 4 * g;
      float pA0 = (((wmA >> (sh + 0)) & 1u) ? 0.f : __expf(aA[0])) * rlA;
      float pA1 = (((wmA >> (sh + 1)) & 1u) ? 0.f : __expf(aA[1])) * rlA;
      float pA2 = (((wmA >> (sh + 2)) & 1u) ? 0.f : __expf(aA[2])) * rlA;
      float pA3 = (((wmA >> (sh + 3)) & 1u) ? 0.f : __expf(aA[3])) * rlA;
      float pB0 = (((wmB >> (sh + 0)) & 1u) ? 0.f : __expf(aB[0])) * rlB;
      float pB1 = (((wmB >> (sh + 1)) & 1u) ? 0.f : __expf(aB[1])) * rlB;
      float pB2 = (((wmB >> (sh + 2)) & 1u) ? 0.f : __expf(aB[2])) * rlB;
      float pB3 = (((wmB >> (sh + 3)) & 1u) ? 0.f : __expf(aB[3])) * rlB;
      *(f32x4*)(arowA + ktg + sh) = (f32x4){pA0, pA1, pA2, pA3};
      *(f32x4*)(arowB + ktg + sh) = (f32x4){pB0, pB1, pB2, pB3};
      bf16x4_t paA = {(__bf16)pA0, (__bf16)pA1, (__bf16)pA2, (__bf16)pA3};
      bf16x4_t paB = {(__bf16)pB0, (__bf16)pB1, (__bf16)pB2, (__bf16)pB3};
      pv8_mfma(cA0, cA1, cA2, cA3, cB0, cB1, cB2, cB3, paA, paB, vf0, vf1, vf2, vf3);
    }
    if (pf) {
      char* Kn = Ks[(tt + 1) & 1];
      char* Vn = Vs[(tt + 1) & 1];
      *(u32x4*)&Kn[kdst] = kr;
      *(unsigned long long*)&Vn[vdst0] = ((unsigned long long)vr[1] << 32) | vr[0];
      *(unsigned long long*)&Vn[vdst1] = ((unsigned long long)vr[3] << 32) | vr[2];
    }
    __syncthreads();
  }
  _Float16* cdst = cp + (size_t)c * CTXN;
  const size_t baseo = (size_t)bh * SN * DN;
  #pragma unroll
  for (int j = 0; j < 4; ++j) {
    const size_t rA = baseo + (size_t)(q0 + 4 * g + j) * DN + qr;
    const size_t rB = baseo + (size_t)(q0 + 16 + 4 * g + j) * DN + qr;
    cdst[rA]      = (_Float16)cA0[j];
    cdst[rA + 16] = (_Float16)cA1[j];
    cdst[rA + 32] = (_Float16)cA2[j];
    cdst[rA + 48] = (_Float16)cA3[j];
    cdst[rB]      = (_Float16)cB0[j];
    cdst[rB + 16] = (_Float16)cB1[j];
    cdst[rB + 32] = (_Float16)cB2[j];
    cdst[rB + 48] = (_Float16)cB3[j];
  }
}

// ---- sum the NK2 f16 partial contexts -> f32 ctx.
__global__ __launch_bounds__(256) void ctx_reduce_kernel(
    const _Float16* __restrict__ cp, float* __restrict__ ctx) {
  const size_t i = ((size_t)blockIdx.x * 256 + threadIdx.x) * 4;
  f16x4 a = *(const f16x4*)(cp + i);
  f16x4 b = *(const f16x4*)(cp + CTXN + i);
  f16x4 d = *(const f16x4*)(cp + 2 * CTXN + i);
  f16x4 e = *(const f16x4*)(cp + 3 * CTXN + i);
  f32x4 s;
  #pragma unroll
  for (int k = 0; k < 4; ++k)
    s[k] = ((float)a[k] + (float)b[k]) + ((float)d[k] + (float)e[k]);
  __builtin_nontemporal_store(s, (f32x4*)(ctx + i));
}

extern "C" void kernel_launch(void* const* d_in, const int* in_sizes, int n_in,
                              void* d_out, int out_size, void* d_ws, size_t ws_size,
                              hipStream_t stream) {
  const float* Q = (const float*)d_in[0];
  const float* K = (const float*)d_in[1];
  const float* V = (const float*)d_in[2];
  const void*  mraw = d_in[3];

  float* out  = (float*)d_out;
  float* ctx  = out;                 // CTXN f32
  float* attn = out + CTXN;          // 67,108,864 f32

  // ws layout (~38.3 MB)
  char* wsb = (char*)d_ws;
  unsigned int* bmT = (unsigned int*)(wsb + 256);                // 8 MB
  float* lp   = (float*)(wsb + 256 + 8388608);                   // 512 KB
  __bf16* Qb  = (__bf16*)(wsb + 256 + 8388608 + 524288);         // 4 MB
  __bf16* Kb  = (__bf16*)(wsb + 256 + 8388608 + 524288 + 4194304);
  __bf16* Vt  = (__bf16*)(wsb + 256 + 8388608 + 524288 + 2 * 4194304);
  _Float16* cp = (_Float16*)(wsb + 256 + 8388608 + 524288 + 3 * 4194304); // 16 MB

  prep_kernel<<<PB + QB + KB + VB, 256, 0, stream>>>(mraw, bmT, Q, K, V, Qb, Kb, Vt);
  attn_l_kernel<<<1024, 256, 0, stream>>>(Qb, Kb, bmT, lp);
  attn_out_kernel<<<1024, 256, 0, stream>>>(Qb, Kb, Vt, bmT, lp, cp, attn);
  ctx_reduce_kernel<<<2048, 256, 0, stream>>>(cp, ctx);
}